// Round 7
// baseline (12424.309 us; speedup 1.0000x reference)
//
#include <hip/hip_runtime.h>

#define H_DIM   2048
#define N_HALF  1024
#define B_SZ    128
#define T_STEPS 512
#define IN_DIM  64
#define ALPHA_F 0.05f
#define OMA_F   0.95f   // 1 - ALPHA

typedef __bf16 bf16x8 __attribute__((ext_vector_type(8)));
typedef float  f32x4  __attribute__((ext_vector_type(4)));

// round-to-nearest-even f32 -> bf16 bits
__device__ __forceinline__ unsigned short f2bf(float f) {
    union { float f; unsigned int u; } v; v.f = f;
    unsigned int u = v.u;
    u += 0x7FFFu + ((u >> 16) & 1u);
    return (unsigned short)(u >> 16);
}

// ---------------------------------------------------------------------------
// Wt[j][k] = bf16(W[k][j])  (transpose + convert, LDS-tiled 64x64)
// ---------------------------------------------------------------------------
__global__ void wt_kernel(const float* __restrict__ W, unsigned short* __restrict__ Wt) {
    __shared__ float tile[64][65];
    const int jb = blockIdx.x * 64;
    const int kb = blockIdx.y * 64;
    const int tx = threadIdx.x;   // 0..63
    const int ty = threadIdx.y;   // 0..3
    #pragma unroll
    for (int r = ty; r < 64; r += 4)
        tile[r][tx] = W[(size_t)(kb + r) * H_DIM + jb + tx];
    __syncthreads();
    #pragma unroll
    for (int r = ty; r < 64; r += 4)
        Wt[(size_t)(jb + r) * H_DIM + kb + tx] = f2bf(tile[tx][r]);
}

// ---------------------------------------------------------------------------
__global__ void vel_kernel(const float* __restrict__ x, const float* __restrict__ w_in,
                           float* __restrict__ vel) {
    const int tb = blockIdx.x * blockDim.x + threadIdx.x;
    if (tb >= T_STEPS * B_SZ) return;
    const float* xp = x + (size_t)tb * IN_DIM;
    float s = 0.f;
    #pragma unroll
    for (int i = 0; i < IN_DIM; i += 4) {
        float4 xv = *reinterpret_cast<const float4*>(xp + i);
        float4 wv = *reinterpret_cast<const float4*>(w_in + i);
        s += xv.x * wv.x + xv.y * wv.y + xv.z * wv.z + xv.w * wv.w;
    }
    vel[tb] = s;
}

// ---------------------------------------------------------------------------
__global__ void hbf_init_kernel(const float* __restrict__ h0, unsigned short* __restrict__ hbf) {
    const int i = blockIdx.x * blockDim.x + threadIdx.x;
    hbf[i] = f2bf(h0[i]);
}

// ---------------------------------------------------------------------------
// Persistent kernel, 512 threads (8 waves) x 256 blocks (1/CU).
// Block tile: 32 batch rows x 32 cols; split-K: waves 0-3 K=[0,1024),
// waves 4-7 K=[1024,2048). Upper waves pass partials via LDS; lower waves
// reduce + epilogue. Sync: per-rowg producer flags, polled by wave 0 only.
// Coherence: all in-loop global stores are relaxed AGENT atomics (L2-bypass);
// A loads plain cached; buffer_inv sc1 after poll drops stale lines.
// B (Wt slice, 128 KB) in LDS forever in MFMA-fragment order.
// ---------------------------------------------------------------------------
__global__ __launch_bounds__(512, 1) void ring_coop_kernel(
        const unsigned short* __restrict__ Wt,
        unsigned short* __restrict__ hbf0,
        unsigned short* __restrict__ hbf1,
        const float* __restrict__ vel,
        const float* __restrict__ hidden0,
        float* __restrict__ acts,
        float* __restrict__ outT,
        unsigned* __restrict__ flags) {
    __shared__ __align__(16) unsigned char ldsB[131072];  // [ch][ks][q][col][16B]
    __shared__ __align__(16) f32x4 pacc[256];             // 4 upper waves x 64 lanes

    const int tid = threadIdx.x;
    const int bid = blockIdx.x;
    // XCD-aware swizzle (bid%8 = XCD round-robin): same-XCD blocks share rowg
    const int rowg = bid & 3;                         // 0..3
    const int colg = (bid >> 3) + ((bid & 4) << 3);   // 0..63
    const int colbase = colg * 32;
    const int rowbase = rowg * 32;

    // ---- one-time: stage B slice into LDS in fragment order ----
    for (int c = tid; c < 8192; c += 512) {
        const int col = c & 15;
        const int q   = (c >> 4) & 3;
        const int ks  = (c >> 6) & 63;
        const int ch  = (c >> 12) & 1;
        const size_t src = (size_t)(colbase + ch * 16 + col) * H_DIM + ks * 32 + q * 8;
        *reinterpret_cast<uint4*>(ldsB + (size_t)c * 16) =
            *reinterpret_cast<const uint4*>(Wt + src);
    }
    __syncthreads();

    const int lane = tid & 63;
    const int w    = tid >> 6;              // 0..7
    const int wlo  = w & 3;                 // tile id 0..3
    const int khalf = w >> 2;               // 0 or 1
    const int rowhalf = wlo >> 1, colhalf = wlo & 1;
    const int wrow = rowbase + rowhalf * 16;
    const int wcol = colbase + colhalf * 16;
    const int r16  = lane & 15;
    const int q4   = lane >> 4;

    const unsigned char* Bp = ldsB + colhalf * 65536 + (khalf * 32) * 1024
                              + q4 * 256 + r16 * 16;
    const int j = wcol + r16;
    const float gamma = (j < N_HALF) ? -1.0f : 1.0f;
    const int brow0 = wrow + q4 * 4;

    unsigned* grp_flags = flags + (rowg << 6);     // 64 flags (one per colg)

    // h_prev in registers (lower waves only): thread owns (brow0..brow0+3, j)
    f32x4 hreg = {0.f, 0.f, 0.f, 0.f};
    if (khalf == 0) {
        #pragma unroll
        for (int i = 0; i < 4; ++i)
            hreg[i] = hidden0[(size_t)(brow0 + i) * H_DIM + j];
    }

#define BFRAG(ss) (*reinterpret_cast<const bf16x8*>(Bp + (size_t)(ss) * 1024))

    for (int t = 0; t < T_STEPS; ++t) {
        const unsigned short* hin  = (t & 1) ? hbf1 : hbf0;
        unsigned short*       hout = (t & 1) ? hbf0 : hbf1;
        const float* vel_t  = vel + (size_t)t * B_SZ;

        if (t > 0) {
            // wave 0 polls this rowg's 64 producers (one 64-lane load/round)
            if (w == 0) {
                while (!__all((int)(__hip_atomic_load(grp_flags + lane,
                                        __ATOMIC_RELAXED, __HIP_MEMORY_SCOPE_AGENT)
                                    >= (unsigned)t))) {
                    __builtin_amdgcn_s_sleep(1);
                }
            }
            __syncthreads();   // release all 8 waves
            // drop stale L1/L2 lines (nothing dirty: in-loop stores bypass L2)
            asm volatile("buffer_inv sc1\n\ts_waitcnt vmcnt(0)" ::: "memory");

            if (khalf == 0) {
                // acts[t-1] from registers: L2-bypassing, overlaps the GEMM
                float* acts_p = acts + (size_t)(t - 1) * B_SZ * H_DIM;
                #pragma unroll
                for (int i = 0; i < 4; ++i)
                    __hip_atomic_store(acts_p + (size_t)(brow0 + i) * H_DIM + j,
                                       hreg[i], __ATOMIC_RELAXED,
                                       __HIP_MEMORY_SCOPE_AGENT);
            }
        }

        // A fragments for this wave's K-half: 32 slices of 16B per lane
        const bf16x8* Ap = reinterpret_cast<const bf16x8*>(
            hin + (size_t)(wrow + r16) * H_DIM + khalf * 1024 + q4 * 8);

        f32x4 acc0 = {0.f,0.f,0.f,0.f}, acc1 = {0.f,0.f,0.f,0.f};
        f32x4 acc2 = {0.f,0.f,0.f,0.f}, acc3 = {0.f,0.f,0.f,0.f};

        bf16x8 a[16];
        #pragma unroll
        for (int s = 0; s < 16; ++s) a[s] = Ap[s * 4];
        #pragma unroll
        for (int s = 0; s < 16; ++s) {
            const bf16x8 av = a[s];
            a[s] = Ap[(s + 16) * 4];
            if ((s & 3) == 0) acc0 = __builtin_amdgcn_mfma_f32_16x16x32_bf16(av, BFRAG(s), acc0, 0, 0, 0);
            if ((s & 3) == 1) acc1 = __builtin_amdgcn_mfma_f32_16x16x32_bf16(av, BFRAG(s), acc1, 0, 0, 0);
            if ((s & 3) == 2) acc2 = __builtin_amdgcn_mfma_f32_16x16x32_bf16(av, BFRAG(s), acc2, 0, 0, 0);
            if ((s & 3) == 3) acc3 = __builtin_amdgcn_mfma_f32_16x16x32_bf16(av, BFRAG(s), acc3, 0, 0, 0);
        }
        #pragma unroll
        for (int s = 16; s < 32; ++s) {
            const bf16x8 av = a[s - 16];
            if ((s & 3) == 0) acc0 = __builtin_amdgcn_mfma_f32_16x16x32_bf16(av, BFRAG(s), acc0, 0, 0, 0);
            if ((s & 3) == 1) acc1 = __builtin_amdgcn_mfma_f32_16x16x32_bf16(av, BFRAG(s), acc1, 0, 0, 0);
            if ((s & 3) == 2) acc2 = __builtin_amdgcn_mfma_f32_16x16x32_bf16(av, BFRAG(s), acc2, 0, 0, 0);
            if ((s & 3) == 3) acc3 = __builtin_amdgcn_mfma_f32_16x16x32_bf16(av, BFRAG(s), acc3, 0, 0, 0);
        }
        f32x4 psum = (acc0 + acc1) + (acc2 + acc3);

        if (khalf == 1) pacc[(size_t)wlo * 64 + lane] = psum;
        __syncthreads();   // partials visible

        if (khalf == 0) {
            const f32x4 vel4 = *reinterpret_cast<const f32x4*>(vel_t + brow0);
            const f32x4 h2h = psum + pacc[(size_t)wlo * 64 + lane];
            #pragma unroll
            for (int i = 0; i < 4; ++i) {
                const int b = brow0 + i;
                const float pre = fmaf(vel4[i], gamma, 1.0f) + h2h[i];
                const float hn = OMA_F * hreg[i] + ALPHA_F * fmaxf(pre, 0.0f);
                hreg[i] = hn;
                __hip_atomic_store(hout + (size_t)b * H_DIM + j, f2bf(hn),
                                   __ATOMIC_RELAXED, __HIP_MEMORY_SCOPE_AGENT);
            }
            asm volatile("s_waitcnt vmcnt(0)" ::: "memory");  // h stores complete
        }
        __syncthreads();   // all lower waves drained
        if (tid == 0)
            __hip_atomic_store(grp_flags + colg, (unsigned)(t + 1),
                               __ATOMIC_RELAXED, __HIP_MEMORY_SCOPE_AGENT);
    }

    // final acts slice + hT (own registers; plain stores, end-of-kernel flush)
    if (khalf == 0) {
        float* acts_last = acts + (size_t)(T_STEPS - 1) * B_SZ * H_DIM;
        #pragma unroll
        for (int i = 0; i < 4; ++i) {
            const size_t off = (size_t)(brow0 + i) * H_DIM + j;
            acts_last[off] = hreg[i];
            outT[off]      = hreg[i];
        }
    }
#undef BFRAG
}

// ---------------------------------------------------------------------------
// Fallback per-step kernel (round-1 proven path) if cooperative launch fails.
// ---------------------------------------------------------------------------
__global__ __launch_bounds__(256) void step_kernel(
        const unsigned short* __restrict__ Wt,
        const unsigned short* __restrict__ hbf_in,
        unsigned short* __restrict__ hbf_out,
        const float* __restrict__ vel_t,
        const float* __restrict__ hprev,
        float* __restrict__ acts_t,
        float* __restrict__ outT) {
    const int lane = threadIdx.x & 63;
    const int w    = threadIdx.x >> 6;
    const int bid  = blockIdx.x;
    const int mg   = bid >> 7;
    const int n    = bid & 127;
    const int base_b = mg * 64 + w * 16;
    const int base_j = n * 16;
    const int r16  = lane & 15;
    const int koff = (lane >> 4) * 8;

    const bf16x8* Ap = reinterpret_cast<const bf16x8*>(
        hbf_in + (size_t)(base_b + r16) * H_DIM + koff);
    const bf16x8* Bp = reinterpret_cast<const bf16x8*>(
        Wt + (size_t)(base_j + r16) * H_DIM + koff);

    f32x4 acc0 = {0.f, 0.f, 0.f, 0.f};
    f32x4 acc1 = {0.f, 0.f, 0.f, 0.f};
    #pragma unroll 4
    for (int kk = 0; kk < 32; ++kk) {
        bf16x8 a0 = Ap[kk * 4];
        bf16x8 b0 = Bp[kk * 4];
        bf16x8 a1 = Ap[kk * 4 + 128];
        bf16x8 b1 = Bp[kk * 4 + 128];
        acc0 = __builtin_amdgcn_mfma_f32_16x16x32_bf16(a0, b0, acc0, 0, 0, 0);
        acc1 = __builtin_amdgcn_mfma_f32_16x16x32_bf16(a1, b1, acc1, 0, 0, 0);
    }
    f32x4 h2h = acc0 + acc1;

    const int j = base_j + r16;
    const float gamma = (j < N_HALF) ? -1.0f : 1.0f;
    const int brow0 = base_b + (lane >> 4) * 4;
    #pragma unroll
    for (int i = 0; i < 4; ++i) {
        const int b = brow0 + i;
        const float v  = vel_t[b];
        const float hp = hprev[(size_t)b * H_DIM + j];
        const float pre = fmaf(v, gamma, 1.0f) + h2h[i];
        const float hn = OMA_F * hp + ALPHA_F * fmaxf(pre, 0.0f);
        acts_t[(size_t)b * H_DIM + j] = hn;
        hbf_out[(size_t)b * H_DIM + j] = f2bf(hn);
        if (outT) outT[(size_t)b * H_DIM + j] = hn;
    }
}

// ---------------------------------------------------------------------------
extern "C" void kernel_launch(void* const* d_in, const int* in_sizes, int n_in,
                              void* d_out, int out_size, void* d_ws, size_t ws_size,
                              hipStream_t stream) {
    const float* x       = (const float*)d_in[0];  // [T,B,IN]
    const float* hidden0 = (const float*)d_in[1];  // [B,H]
    const float* w_attr  = (const float*)d_in[2];  // [H,H]
    const float* w_in    = (const float*)d_in[3];  // [1,IN]

    float* acts = (float*)d_out;                               // [T,B,H]
    float* outT = acts + (size_t)T_STEPS * B_SZ * H_DIM;       // [B,H]

    unsigned char* ws = (unsigned char*)d_ws;
    unsigned short* Wt   = (unsigned short*)ws;                             // 8 MB
    unsigned short* hbf0 = (unsigned short*)(ws + ((size_t)8 << 20));       // 512 KB
    unsigned short* hbf1 = hbf0 + (size_t)B_SZ * H_DIM;                     // 512 KB
    float* vel = (float*)(ws + ((size_t)8 << 20) + (size_t)2 * B_SZ * H_DIM * 2); // 256 KB
    unsigned* flags = (unsigned*)(ws + ((size_t)8 << 20) + ((size_t)1 << 20) + (256 << 10)); // 1 KB

    hipMemsetAsync(flags, 0, 4096, stream);
    wt_kernel<<<dim3(32, 32), dim3(64, 4), 0, stream>>>(w_attr, Wt);
    vel_kernel<<<(T_STEPS * B_SZ + 255) / 256, 256, 0, stream>>>(x, w_in, vel);
    hbf_init_kernel<<<(B_SZ * H_DIM + 255) / 256, 256, 0, stream>>>(hidden0, hbf0);

    void* args[] = {(void*)&Wt, (void*)&hbf0, (void*)&hbf1, (void*)&vel,
                    (void*)&hidden0, (void*)&acts, (void*)&outT, (void*)&flags};
    hipError_t rc = hipLaunchCooperativeKernel(
        reinterpret_cast<void*>(ring_coop_kernel),
        dim3(256), dim3(512), args, 0, stream);

    if (rc != hipSuccess) {
        // fallback: per-step launches (round-1 path)
        for (int t = 0; t < T_STEPS; ++t) {
            const unsigned short* hin = (t & 1) ? hbf1 : hbf0;
            unsigned short* hout      = (t & 1) ? hbf0 : hbf1;
            const float* hprev = (t == 0) ? hidden0 : acts + (size_t)(t - 1) * B_SZ * H_DIM;
            step_kernel<<<256, 256, 0, stream>>>(
                Wt, hin, hout, vel + (size_t)t * B_SZ, hprev,
                acts + (size_t)t * B_SZ * H_DIM,
                (t == T_STEPS - 1) ? outT : nullptr);
        }
    }
}

// Round 9
// 9411.079 us; speedup vs baseline: 1.3202x; 1.3202x over previous
//
#include <hip/hip_runtime.h>

#define H_DIM   2048
#define N_HALF  1024
#define B_SZ    128
#define T_STEPS 512
#define IN_DIM  64
#define ALPHA_F 0.05f
#define OMA_F   0.95f   // 1 - ALPHA

typedef __bf16 bf16x8 __attribute__((ext_vector_type(8)));
typedef float  f32x4  __attribute__((ext_vector_type(4)));

// round-to-nearest-even f32 -> bf16 bits
__device__ __forceinline__ unsigned short f2bf(float f) {
    union { float f; unsigned int u; } v; v.f = f;
    unsigned int u = v.u;
    u += 0x7FFFu + ((u >> 16) & 1u);
    return (unsigned short)(u >> 16);
}

// ---------------------------------------------------------------------------
// Wt[j][k] = bf16(W[k][j])  (transpose + convert, LDS-tiled 64x64)
// ---------------------------------------------------------------------------
__global__ void wt_kernel(const float* __restrict__ W, unsigned short* __restrict__ Wt) {
    __shared__ float tile[64][65];
    const int jb = blockIdx.x * 64;
    const int kb = blockIdx.y * 64;
    const int tx = threadIdx.x;   // 0..63
    const int ty = threadIdx.y;   // 0..3
    #pragma unroll
    for (int r = ty; r < 64; r += 4)
        tile[r][tx] = W[(size_t)(kb + r) * H_DIM + jb + tx];
    __syncthreads();
    #pragma unroll
    for (int r = ty; r < 64; r += 4)
        Wt[(size_t)(jb + r) * H_DIM + kb + tx] = f2bf(tile[tx][r]);
}

// ---------------------------------------------------------------------------
__global__ void vel_kernel(const float* __restrict__ x, const float* __restrict__ w_in,
                           float* __restrict__ vel) {
    const int tb = blockIdx.x * blockDim.x + threadIdx.x;
    if (tb >= T_STEPS * B_SZ) return;
    const float* xp = x + (size_t)tb * IN_DIM;
    float s = 0.f;
    #pragma unroll
    for (int i = 0; i < IN_DIM; i += 4) {
        float4 xv = *reinterpret_cast<const float4*>(xp + i);
        float4 wv = *reinterpret_cast<const float4*>(w_in + i);
        s += xv.x * wv.x + xv.y * wv.y + xv.z * wv.z + xv.w * wv.w;
    }
    vel[tb] = s;
}

// ---------------------------------------------------------------------------
__global__ void hbf_init_kernel(const float* __restrict__ h0, unsigned short* __restrict__ hbf) {
    const int i = blockIdx.x * blockDim.x + threadIdx.x;
    hbf[i] = f2bf(h0[i]);
}

// ---------------------------------------------------------------------------
// Two-level grid barrier (256 blocks = 16 groups x 16)  [round-5 proven].
// Monotone counters (memset to 0 per launch -> deterministic).
// ---------------------------------------------------------------------------
__device__ __forceinline__ void ring_barrier(unsigned* bar, int t, int bid, int tid) {
    asm volatile("s_waitcnt vmcnt(0)" ::: "memory");  // h/acts stores complete
    __syncthreads();                                   // all waves drained
    if (tid == 0) {
        unsigned* gcnt = bar + (bid >> 4) * 32;
        unsigned* rcnt = bar + 16 * 32;
        unsigned* gen  = bar + 16 * 32 + 32;
        unsigned old = __hip_atomic_fetch_add(gcnt, 1u, __ATOMIC_RELAXED,
                                              __HIP_MEMORY_SCOPE_AGENT);
        if (old == (unsigned)(t * 16 + 15)) {                 // last block of group
            unsigned r = __hip_atomic_fetch_add(rcnt, 1u, __ATOMIC_RELAXED,
                                                __HIP_MEMORY_SCOPE_AGENT);
            if (r == (unsigned)(t * 16 + 15)) {               // last group
                __hip_atomic_store(gen, (unsigned)(t + 1), __ATOMIC_RELAXED,
                                   __HIP_MEMORY_SCOPE_AGENT);
            }
        }
        while (__hip_atomic_load(gen, __ATOMIC_RELAXED, __HIP_MEMORY_SCOPE_AGENT)
               < (unsigned)(t + 1)) {
            __builtin_amdgcn_s_sleep(1);
        }
    }
    __syncthreads();
    // Acquire: drop stale L1/L2 lines. Nothing dirty can be lost: every
    // in-loop global store bypasses L2 (agent atomics / sc0 sc1 stores).
    asm volatile("buffer_inv sc1\n\ts_waitcnt vmcnt(0)" ::: "memory");
}

// ---------------------------------------------------------------------------
// Persistent kernel [round-5 protocol + batched A loads + nt acts stores].
// 256 blocks (1/CU) x 256 threads (4 waves). Block tile: 32 rows x 32 cols.
// XCD swizzle: rowg = bid&3 -> same-XCD blocks share the 32 A-rows.
// B (Wt slice, 128 KB) in LDS forever in MFMA-fragment order.
// Per step: ALL 64 A-fragment loads issued first (one exposed latency),
// sched_barrier fence, then 64 MFMAs off LDS B. acts -> nt streamed to HBM
// (keeps h L3-resident); h handoff via agent atomics; buffer_inv acquire.
// ---------------------------------------------------------------------------
__global__ __launch_bounds__(256, 1) void ring_coop_kernel(
        const unsigned short* __restrict__ Wt,
        unsigned short* __restrict__ hbf0,
        unsigned short* __restrict__ hbf1,
        const float* __restrict__ vel,
        const float* __restrict__ hidden0,
        float* __restrict__ acts,
        float* __restrict__ outT,
        unsigned* __restrict__ bar) {
    __shared__ __align__(16) unsigned char ldsB[131072];  // [ch][ks][q][col][16B]

    const int tid = threadIdx.x;
    const int bid = blockIdx.x;
    // XCD-aware swizzle (bid%8 = XCD round-robin): same-XCD blocks share rowg
    const int rowg = bid & 3;                         // 0..3
    const int colg = (bid >> 3) + ((bid & 4) << 3);   // 0..63
    const int colbase = colg * 32;
    const int rowbase = rowg * 32;

    // ---- one-time: stage B slice into LDS in fragment order ----
    for (int c = tid; c < 8192; c += 256) {
        const int col = c & 15;
        const int q   = (c >> 4) & 3;
        const int ks  = (c >> 6) & 63;
        const int ch  = (c >> 12) & 1;
        const size_t src = (size_t)(colbase + ch * 16 + col) * H_DIM + ks * 32 + q * 8;
        *reinterpret_cast<uint4*>(ldsB + (size_t)c * 16) =
            *reinterpret_cast<const uint4*>(Wt + src);
    }
    __syncthreads();

    const int lane = tid & 63;
    const int w    = tid >> 6;              // 0..3
    const int rowhalf = w >> 1, colhalf = w & 1;
    const int wrow = rowbase + rowhalf * 16;
    const int wcol = colbase + colhalf * 16;
    const int r16  = lane & 15;
    const int q4   = lane >> 4;

    const unsigned char* Bp = ldsB + colhalf * 65536 + q4 * 256 + r16 * 16;
    const int j = wcol + r16;
    const float gamma = (j < N_HALF) ? -1.0f : 1.0f;
    const int brow0 = wrow + q4 * 4;

    // h_prev in registers: this thread owns (brow0..brow0+3, j)
    f32x4 hreg;
    #pragma unroll
    for (int i = 0; i < 4; ++i)
        hreg[i] = hidden0[(size_t)(brow0 + i) * H_DIM + j];

#define BFRAG(ss) (*reinterpret_cast<const bf16x8*>(Bp + (size_t)(ss) * 1024))

    for (int t = 0; t < T_STEPS; ++t) {
        const unsigned short* hin  = (t & 1) ? hbf1 : hbf0;
        unsigned short*       hout = (t & 1) ? hbf0 : hbf1;
        const float* vel_t  = vel + (size_t)t * B_SZ;

        const bf16x8* Ap = reinterpret_cast<const bf16x8*>(
            hin + (size_t)(wrow + r16) * H_DIM + q4 * 8);

        // ---- issue ALL 64 A-fragment loads (4 chains x 16 slices) ----
        bf16x8 A0[16], A1[16], A2[16], A3[16];
        #pragma unroll
        for (int s = 0; s < 16; ++s) {
            A0[s] = Ap[s * 4];
            A1[s] = Ap[s * 4 + 64];
            A2[s] = Ap[s * 4 + 128];
            A3[s] = Ap[s * 4 + 192];
        }
        __builtin_amdgcn_sched_barrier(0);   // keep loads issued before MFMAs

        const f32x4 vel4 = *reinterpret_cast<const f32x4*>(vel_t + brow0);

        f32x4 acc0 = {0.f,0.f,0.f,0.f}, acc1 = {0.f,0.f,0.f,0.f};
        f32x4 acc2 = {0.f,0.f,0.f,0.f}, acc3 = {0.f,0.f,0.f,0.f};
        #pragma unroll
        for (int s = 0; s < 16; ++s) {
            acc0 = __builtin_amdgcn_mfma_f32_16x16x32_bf16(A0[s], BFRAG(s),      acc0, 0, 0, 0);
            acc1 = __builtin_amdgcn_mfma_f32_16x16x32_bf16(A1[s], BFRAG(s + 16), acc1, 0, 0, 0);
            acc2 = __builtin_amdgcn_mfma_f32_16x16x32_bf16(A2[s], BFRAG(s + 32), acc2, 0, 0, 0);
            acc3 = __builtin_amdgcn_mfma_f32_16x16x32_bf16(A3[s], BFRAG(s + 48), acc3, 0, 0, 0);
        }
        f32x4 h2h = (acc0 + acc1) + (acc2 + acc3);

        // acts[t-1] = h_t from registers: L2-bypass + non-temporal (stream to
        // HBM without polluting L3, so the h buffers stay L3-resident).
        if (t > 0) {
            float* acts_p = acts + (size_t)(t - 1) * B_SZ * H_DIM;
            #pragma unroll
            for (int i = 0; i < 4; ++i) {
                float* ap = acts_p + (size_t)(brow0 + i) * H_DIM + j;
                float  vv = hreg[i];
                asm volatile("global_store_dword %0, %1, off sc0 sc1 nt"
                             :: "v"(ap), "v"(vv) : "memory");
            }
        }

        #pragma unroll
        for (int i = 0; i < 4; ++i) {
            const int b = brow0 + i;
            const float pre = fmaf(vel4[i], gamma, 1.0f) + h2h[i];
            const float hn = OMA_F * hreg[i] + ALPHA_F * fmaxf(pre, 0.0f);
            hreg[i] = hn;
            __hip_atomic_store(hout + (size_t)b * H_DIM + j, f2bf(hn),
                               __ATOMIC_RELAXED, __HIP_MEMORY_SCOPE_AGENT);
        }

        ring_barrier(bar, t, bid, tid);
    }

    // final acts slice + hT (own registers; plain stores, end-of-kernel flush)
    float* acts_last = acts + (size_t)(T_STEPS - 1) * B_SZ * H_DIM;
    #pragma unroll
    for (int i = 0; i < 4; ++i) {
        const size_t off = (size_t)(brow0 + i) * H_DIM + j;
        acts_last[off] = hreg[i];
        outT[off]      = hreg[i];
    }
#undef BFRAG
}

// ---------------------------------------------------------------------------
// Fallback per-step kernel (round-1 proven path) if cooperative launch fails.
// ---------------------------------------------------------------------------
__global__ __launch_bounds__(256) void step_kernel(
        const unsigned short* __restrict__ Wt,
        const unsigned short* __restrict__ hbf_in,
        unsigned short* __restrict__ hbf_out,
        const float* __restrict__ vel_t,
        const float* __restrict__ hprev,
        float* __restrict__ acts_t,
        float* __restrict__ outT) {
    const int lane = threadIdx.x & 63;
    const int w    = threadIdx.x >> 6;
    const int bid  = blockIdx.x;
    const int mg   = bid >> 7;
    const int n    = bid & 127;
    const int base_b = mg * 64 + w * 16;
    const int base_j = n * 16;
    const int r16  = lane & 15;
    const int koff = (lane >> 4) * 8;

    const bf16x8* Ap = reinterpret_cast<const bf16x8*>(
        hbf_in + (size_t)(base_b + r16) * H_DIM + koff);
    const bf16x8* Bp = reinterpret_cast<const bf16x8*>(
        Wt + (size_t)(base_j + r16) * H_DIM + koff);

    f32x4 acc0 = {0.f, 0.f, 0.f, 0.f};
    f32x4 acc1 = {0.f, 0.f, 0.f, 0.f};
    #pragma unroll 4
    for (int kk = 0; kk < 32; ++kk) {
        bf16x8 a0 = Ap[kk * 4];
        bf16x8 b0 = Bp[kk * 4];
        bf16x8 a1 = Ap[kk * 4 + 128];
        bf16x8 b1 = Bp[kk * 4 + 128];
        acc0 = __builtin_amdgcn_mfma_f32_16x16x32_bf16(a0, b0, acc0, 0, 0, 0);
        acc1 = __builtin_amdgcn_mfma_f32_16x16x32_bf16(a1, b1, acc1, 0, 0, 0);
    }
    f32x4 h2h = acc0 + acc1;

    const int j = base_j + r16;
    const float gamma = (j < N_HALF) ? -1.0f : 1.0f;
    const int brow0 = base_b + (lane >> 4) * 4;
    #pragma unroll
    for (int i = 0; i < 4; ++i) {
        const int b = brow0 + i;
        const float v  = vel_t[b];
        const float hp = hprev[(size_t)b * H_DIM + j];
        const float pre = fmaf(v, gamma, 1.0f) + h2h[i];
        const float hn = OMA_F * hp + ALPHA_F * fmaxf(pre, 0.0f);
        acts_t[(size_t)b * H_DIM + j] = hn;
        hbf_out[(size_t)b * H_DIM + j] = f2bf(hn);
        if (outT) outT[(size_t)b * H_DIM + j] = hn;
    }
}

// ---------------------------------------------------------------------------
extern "C" void kernel_launch(void* const* d_in, const int* in_sizes, int n_in,
                              void* d_out, int out_size, void* d_ws, size_t ws_size,
                              hipStream_t stream) {
    const float* x       = (const float*)d_in[0];  // [T,B,IN]
    const float* hidden0 = (const float*)d_in[1];  // [B,H]
    const float* w_attr  = (const float*)d_in[2];  // [H,H]
    const float* w_in    = (const float*)d_in[3];  // [1,IN]

    float* acts = (float*)d_out;                               // [T,B,H]
    float* outT = acts + (size_t)T_STEPS * B_SZ * H_DIM;       // [B,H]

    unsigned char* ws = (unsigned char*)d_ws;
    unsigned short* Wt   = (unsigned short*)ws;                             // 8 MB
    unsigned short* hbf0 = (unsigned short*)(ws + ((size_t)8 << 20));       // 512 KB
    unsigned short* hbf1 = hbf0 + (size_t)B_SZ * H_DIM;                     // 512 KB
    float* vel = (float*)(ws + ((size_t)8 << 20) + (size_t)2 * B_SZ * H_DIM * 2); // 256 KB
    unsigned* bar = (unsigned*)(ws + ((size_t)8 << 20) + ((size_t)1 << 20) + (256 << 10)); // 4 KB

    hipMemsetAsync(bar, 0, 4096, stream);
    wt_kernel<<<dim3(32, 32), dim3(64, 4), 0, stream>>>(w_attr, Wt);
    vel_kernel<<<(T_STEPS * B_SZ + 255) / 256, 256, 0, stream>>>(x, w_in, vel);
    hbf_init_kernel<<<(B_SZ * H_DIM + 255) / 256, 256, 0, stream>>>(hidden0, hbf0);

    void* args[] = {(void*)&Wt, (void*)&hbf0, (void*)&hbf1, (void*)&vel,
                    (void*)&hidden0, (void*)&acts, (void*)&outT, (void*)&bar};
    hipError_t rc = hipLaunchCooperativeKernel(
        reinterpret_cast<void*>(ring_coop_kernel),
        dim3(256), dim3(256), args, 0, stream);

    if (rc != hipSuccess) {
        // fallback: per-step launches (round-1 path)
        for (int t = 0; t < T_STEPS; ++t) {
            const unsigned short* hin = (t & 1) ? hbf1 : hbf0;
            unsigned short* hout      = (t & 1) ? hbf0 : hbf1;
            const float* hprev = (t == 0) ? hidden0 : acts + (size_t)(t - 1) * B_SZ * H_DIM;
            step_kernel<<<256, 256, 0, stream>>>(
                Wt, hin, hout, vel + (size_t)t * B_SZ, hprev,
                acts + (size_t)t * B_SZ * H_DIM,
                (t == T_STEPS - 1) ? outT : nullptr);
        }
    }
}

// Round 10
// 3652.851 us; speedup vs baseline: 3.4013x; 2.5764x over previous
//
#include <hip/hip_runtime.h>

#define H_DIM   2048
#define N_HALF  1024
#define B_SZ    128
#define T_STEPS 512
#define IN_DIM  64
#define ALPHA_F 0.05f
#define OMA_F   0.95f   // 1 - ALPHA

typedef __bf16 bf16x8 __attribute__((ext_vector_type(8)));
typedef float  f32x4  __attribute__((ext_vector_type(4)));
typedef unsigned int u32x4 __attribute__((ext_vector_type(4)));

// round-to-nearest-even f32 -> bf16 bits
__device__ __forceinline__ unsigned short f2bf(float f) {
    union { float f; unsigned int u; } v; v.f = f;
    unsigned int u = v.u;
    u += 0x7FFFu + ((u >> 16) & 1u);
    return (unsigned short)(u >> 16);
}

// ---------------------------------------------------------------------------
// Wf: weights in MFMA-fragment order (validated by construction, round 8
// derivation re-checked):
//   Wf[(j>>6)*131072 + ((ks*4 + q4)*64 + (j&63))*8 + e] = bf16(W[k][j])
//   with ks = k>>5, q4 = (k>>3)&3, e = k&7.
// A lane's 16B B-fragment (col j, k-slice ks) is one contiguous chunk, and
// adjacent lanes read adjacent chunks -> fully coalesced B streams.
// ---------------------------------------------------------------------------
__global__ void wf_kernel(const float* __restrict__ W, unsigned short* __restrict__ Wf) {
    __shared__ float tile[64][65];     // tile[kk][jj] = W[kb+kk][jb+jj]
    const int jb = blockIdx.x * 64;
    const int kb = blockIdx.y * 64;
    const int t  = threadIdx.y * 64 + threadIdx.x;   // 0..255
    const int tx = threadIdx.x, ty = threadIdx.y;
    #pragma unroll
    for (int r = ty; r < 64; r += 4)
        tile[r][tx] = W[(size_t)(kb + r) * H_DIM + jb + tx];
    __syncthreads();
    #pragma unroll
    for (int cc = 0; cc < 2; ++cc) {
        const int c  = t * 2 + cc;        // 0..511
        const int jj = c >> 3;            // 0..63
        const int kc = c & 7;             // 8-K group within tile
        const int j  = jb + jj;
        const int k0 = kb + kc * 8;
        unsigned short v[8];
        #pragma unroll
        for (int e = 0; e < 8; ++e)
            v[e] = f2bf(tile[kc * 8 + e][jj]);
        const int ks = k0 >> 5;
        const int q4 = (k0 >> 3) & 3;
        const size_t dst = (size_t)(j >> 6) * 131072 +
                           ((size_t)(ks * 4 + q4) * 64 + (j & 63)) * 8;
        *reinterpret_cast<u32x4*>(Wf + dst) = *reinterpret_cast<u32x4*>(v);
    }
}

// ---------------------------------------------------------------------------
__global__ void vel_kernel(const float* __restrict__ x, const float* __restrict__ w_in,
                           float* __restrict__ vel) {
    const int tb = blockIdx.x * blockDim.x + threadIdx.x;
    if (tb >= T_STEPS * B_SZ) return;
    const float* xp = x + (size_t)tb * IN_DIM;
    float s = 0.f;
    #pragma unroll
    for (int i = 0; i < IN_DIM; i += 4) {
        float4 xv = *reinterpret_cast<const float4*>(xp + i);
        float4 wv = *reinterpret_cast<const float4*>(w_in + i);
        s += xv.x * wv.x + xv.y * wv.y + xv.z * wv.z + xv.w * wv.w;
    }
    vel[tb] = s;
}

// ---------------------------------------------------------------------------
__global__ void hbf_init_kernel(const float* __restrict__ h0, unsigned short* __restrict__ hbf) {
    const int i = blockIdx.x * blockDim.x + threadIdx.x;
    hbf[i] = f2bf(h0[i]);
}

// ---------------------------------------------------------------------------
// Two-level grid barrier (256 blocks = 16 groups x 16)  [round-5 proven,
// buffer_inv REMOVED: no cached reads of mutable data remain].
// ---------------------------------------------------------------------------
__device__ __forceinline__ void ring_barrier(unsigned* bar, int t, int bid, int tid) {
    asm volatile("s_waitcnt vmcnt(0)" ::: "memory");
    __syncthreads();
    if (tid == 0) {
        unsigned* gcnt = bar + (bid >> 4) * 32;
        unsigned* rcnt = bar + 16 * 32;
        unsigned* gen  = bar + 16 * 32 + 32;
        unsigned old = __hip_atomic_fetch_add(gcnt, 1u, __ATOMIC_RELAXED,
                                              __HIP_MEMORY_SCOPE_AGENT);
        if (old == (unsigned)(t * 16 + 15)) {
            unsigned r = __hip_atomic_fetch_add(rcnt, 1u, __ATOMIC_RELAXED,
                                                __HIP_MEMORY_SCOPE_AGENT);
            if (r == (unsigned)(t * 16 + 15)) {
                __hip_atomic_store(gen, (unsigned)(t + 1), __ATOMIC_RELAXED,
                                   __HIP_MEMORY_SCOPE_AGENT);
            }
        }
        while (__hip_atomic_load(gen, __ATOMIC_RELAXED, __HIP_MEMORY_SCOPE_AGENT)
               < (unsigned)(t + 1)) {
            __builtin_amdgcn_s_sleep(1);
        }
    }
    __syncthreads();
}

// ---------------------------------------------------------------------------
// Persistent kernel: 256 blocks (1/CU) x 512 threads (8 waves).
// Block tile 16 rows x 64 cols; 8 waves = 4 col-quarters x 2 K-halves.
// Per step: A-panel (16x2048 bf16, 64 KB) staged to LDS in fragment order via
// sc0+sc1 (L2-bypass) loads -> unique-ish 16 MB/step grid-wide (vs 64 before).
// B streamed per-fragment from Wf, CACHED: XCD-local L2-resident forever
// (colg-partitioned via bid%8 swizzle; W immutable; no buffer_inv anywhere).
// Epilogue: K-pair LDS reduce, h_new via LDS transpose -> 16B bf16x8 h stores
// (sc0 sc1) + 16B f32x4 nt acts stores. h_prev in registers. r5 tree barrier.
// ---------------------------------------------------------------------------
__global__ __launch_bounds__(512, 1) void ring_coop_kernel(
        const unsigned short* __restrict__ Wf,
        unsigned short* __restrict__ hbf0,
        unsigned short* __restrict__ hbf1,
        const float* __restrict__ vel,
        const float* __restrict__ hidden0,
        float* __restrict__ acts,
        float* __restrict__ outT,
        unsigned* __restrict__ bar) {
    __shared__ __align__(16) unsigned char A_lds[65536];   // frag chunk (kc*16+row)*16B
    __shared__ __align__(16) f32x4 pacc[256];              // [colq][lane]
    __shared__ __align__(16) float hbuf[16][64];           // epilogue transpose

    const int tid = threadIdx.x;
    const int bid = blockIdx.x;
    // XCD swizzle (bid%8 = XCD): XCD x owns colgs {4x..4x+3} for ALL rowgs ->
    // B working set 1 MB per XCD, L2-resident across all 512 steps.
    const int colg = (bid & 7) * 4 + ((bid >> 3) & 3);   // 0..31 (64-col groups)
    const int rowg = bid >> 5;                            // 0..7  (16-row groups)
    const int colbase = colg * 64;
    const int rowbase = rowg * 16;

    const int lane = tid & 63, w = tid >> 6;   // 8 waves
    const int colq = w & 3, khalf = w >> 2;
    const int r16 = lane & 15, q4 = lane >> 4;
    const int j = colbase + colq * 16 + r16;
    const float gamma = (j < N_HALF) ? -1.0f : 1.0f;
    const unsigned short* wslot = Wf + (size_t)colg * 131072;

    // A-staging assignment: thread -> row = tid>>5 (32 threads/row), kb = tid&31
    const int srow = tid >> 5;
    const int kb   = tid & 31;

    // h_prev registers (khalf==0 waves): rows rowbase+q4*4+i, col j
    f32x4 hreg = {0.f, 0.f, 0.f, 0.f};
    if (khalf == 0) {
        #pragma unroll
        for (int i = 0; i < 4; ++i)
            hreg[i] = hidden0[(size_t)(rowbase + q4 * 4 + i) * H_DIM + j];
    }

    for (int t = 0; t < T_STEPS; ++t) {
        const unsigned short* hin  = (t & 1) ? hbf1 : hbf0;
        unsigned short*       hout = (t & 1) ? hbf0 : hbf1;
        const float* vel_t = vel + (size_t)t * B_SZ;
        float* acts_t = acts + (size_t)t * B_SZ * H_DIM;

        // ---- stage A panel (16 rows x 2048) to LDS, fragment order ----
        // 8 chunks of 16B per thread; sc0+sc1 loads (L2-bypass -> always fresh)
        {
            const unsigned short* ap = hin + (size_t)(rowbase + srow) * H_DIM + kb * 8;
            u32x4 av0, av1, av2, av3, av4, av5, av6, av7;
            asm volatile("global_load_dwordx4 %0, %1, off sc0 sc1" : "=v"(av0) : "v"(ap));
            asm volatile("global_load_dwordx4 %0, %1, off sc0 sc1" : "=v"(av1) : "v"(ap + 256));
            asm volatile("global_load_dwordx4 %0, %1, off sc0 sc1" : "=v"(av2) : "v"(ap + 512));
            asm volatile("global_load_dwordx4 %0, %1, off sc0 sc1" : "=v"(av3) : "v"(ap + 768));
            asm volatile("global_load_dwordx4 %0, %1, off sc0 sc1" : "=v"(av4) : "v"(ap + 1024));
            asm volatile("global_load_dwordx4 %0, %1, off sc0 sc1" : "=v"(av5) : "v"(ap + 1280));
            asm volatile("global_load_dwordx4 %0, %1, off sc0 sc1" : "=v"(av6) : "v"(ap + 1536));
            asm volatile("global_load_dwordx4 %0, %1, off sc0 sc1" : "=v"(av7) : "v"(ap + 1792));
            asm volatile("s_waitcnt vmcnt(0)" ::: "memory");
            __builtin_amdgcn_sched_barrier(0);
            // LDS chunk index = kc*16 + row, kc = kb + i*32
            unsigned char* ad = A_lds + ((size_t)kb * 16 + srow) * 16;
            *reinterpret_cast<u32x4*>(ad)               = av0;
            *reinterpret_cast<u32x4*>(ad + 32 * 256)    = av1;
            *reinterpret_cast<u32x4*>(ad + 64 * 256)    = av2;
            *reinterpret_cast<u32x4*>(ad + 96 * 256)    = av3;
            *reinterpret_cast<u32x4*>(ad + 128 * 256)   = av4;
            *reinterpret_cast<u32x4*>(ad + 160 * 256)   = av5;
            *reinterpret_cast<u32x4*>(ad + 192 * 256)   = av6;
            *reinterpret_cast<u32x4*>(ad + 224 * 256)   = av7;
        }
        __syncthreads();

        // ---- GEMM: 32 MFMAs per wave (K-half of 1024), B from L2 (cached) ----
        // A chunk (khalf*32+s)*4+q4, row r16 -> byte ((khalf*128+s*4+q4)*16+r16)*16
        const unsigned char* abase = A_lds + ((size_t)(khalf * 128 + q4) * 16 + r16) * 16;
        const unsigned short* bgbase = wslot + (size_t)(khalf * 128 + q4) * 512
                                       + (size_t)(colq * 16 + r16) * 8;
        f32x4 acc0 = {0.f,0.f,0.f,0.f}, acc1 = {0.f,0.f,0.f,0.f};
        f32x4 acc2 = {0.f,0.f,0.f,0.f}, acc3 = {0.f,0.f,0.f,0.f};
        #pragma unroll
        for (int s = 0; s < 32; s += 4) {
            bf16x8 b0 = *reinterpret_cast<const bf16x8*>(bgbase + (size_t)(s + 0) * 2048);
            bf16x8 b1 = *reinterpret_cast<const bf16x8*>(bgbase + (size_t)(s + 1) * 2048);
            bf16x8 b2 = *reinterpret_cast<const bf16x8*>(bgbase + (size_t)(s + 2) * 2048);
            bf16x8 b3 = *reinterpret_cast<const bf16x8*>(bgbase + (size_t)(s + 3) * 2048);
            bf16x8 a0 = *reinterpret_cast<const bf16x8*>(abase + (size_t)(s + 0) * 1024);
            bf16x8 a1 = *reinterpret_cast<const bf16x8*>(abase + (size_t)(s + 1) * 1024);
            bf16x8 a2 = *reinterpret_cast<const bf16x8*>(abase + (size_t)(s + 2) * 1024);
            bf16x8 a3 = *reinterpret_cast<const bf16x8*>(abase + (size_t)(s + 3) * 1024);
            acc0 = __builtin_amdgcn_mfma_f32_16x16x32_bf16(a0, b0, acc0, 0, 0, 0);
            acc1 = __builtin_amdgcn_mfma_f32_16x16x32_bf16(a1, b1, acc1, 0, 0, 0);
            acc2 = __builtin_amdgcn_mfma_f32_16x16x32_bf16(a2, b2, acc2, 0, 0, 0);
            acc3 = __builtin_amdgcn_mfma_f32_16x16x32_bf16(a3, b3, acc3, 0, 0, 0);
        }
        f32x4 psum = (acc0 + acc1) + (acc2 + acc3);

        // ---- K-pair reduce + epilogue into hbuf ----
        if (khalf == 1) pacc[colq * 64 + lane] = psum;
        __syncthreads();
        if (khalf == 0) {
            const f32x4 h2h = psum + pacc[colq * 64 + lane];
            const f32x4 vel4 = *reinterpret_cast<const f32x4*>(vel_t + rowbase + q4 * 4);
            #pragma unroll
            for (int i = 0; i < 4; ++i) {
                const float pre = fmaf(vel4[i], gamma, 1.0f) + h2h[i];
                const float hn = OMA_F * hreg[i] + ALPHA_F * fmaxf(pre, 0.0f);
                hreg[i] = hn;
                hbuf[q4 * 4 + i][colq * 16 + r16] = hn;
            }
        }
        __syncthreads();

        // ---- wide bypass stores from hbuf ----
        if (tid < 128) {           // h bf16: 16 rows x 64 cols / 8 = 128 x 16B
            const int row2 = tid >> 3, c8 = (tid & 7) * 8;
            unsigned pk[4];
            #pragma unroll
            for (int e = 0; e < 4; ++e)
                pk[e] = (unsigned)f2bf(hbuf[row2][c8 + 2 * e]) |
                        ((unsigned)f2bf(hbuf[row2][c8 + 2 * e + 1]) << 16);
            u32x4 hv = {pk[0], pk[1], pk[2], pk[3]};
            unsigned short* dst = hout + (size_t)(rowbase + row2) * H_DIM + colbase + c8;
            asm volatile("global_store_dwordx4 %0, %1, off sc0 sc1"
                         :: "v"(dst), "v"(hv) : "memory");
        }
        if (tid < 256) {           // acts f32: 16 x 64 / 4 = 256 x 16B, nt
            const int row3 = tid >> 4, c4 = (tid & 15) * 4;
            f32x4 va = *reinterpret_cast<const f32x4*>(&hbuf[row3][c4]);
            float* dst = acts_t + (size_t)(rowbase + row3) * H_DIM + colbase + c4;
            asm volatile("global_store_dwordx4 %0, %1, off sc0 sc1 nt"
                         :: "v"(dst), "v"(va) : "memory");
        }
        if (t == T_STEPS - 1 && tid >= 256) {   // hT tail (plain, end-of-kernel flush)
            const int t2 = tid - 256;
            const int row3 = t2 >> 4, c4 = (t2 & 15) * 4;
            f32x4 va = *reinterpret_cast<const f32x4*>(&hbuf[row3][c4]);
            *reinterpret_cast<f32x4*>(outT + (size_t)(rowbase + row3) * H_DIM + colbase + c4) = va;
        }

        if (t < T_STEPS - 1) ring_barrier(bar, t, bid, tid);
    }
}

// ---------------------------------------------------------------------------
// Fallback per-step kernel (Wf layout; round-8 derivation re-validated).
// ---------------------------------------------------------------------------
__global__ __launch_bounds__(256) void step_kernel(
        const unsigned short* __restrict__ Wf,
        const unsigned short* __restrict__ hbf_in,
        unsigned short* __restrict__ hbf_out,
        const float* __restrict__ vel_t,
        const float* __restrict__ hprev,
        float* __restrict__ acts_t,
        float* __restrict__ outT) {
    const int lane = threadIdx.x & 63;
    const int w    = threadIdx.x >> 6;
    const int bid  = blockIdx.x;
    const int mg   = bid >> 7;
    const int n    = bid & 127;
    const int base_b = mg * 64 + w * 16;
    const int base_j = n * 16;
    const int r16  = lane & 15;
    const int q4   = lane >> 4;

    const int j = base_j + r16;
    const bf16x8* Ap = reinterpret_cast<const bf16x8*>(
        hbf_in + (size_t)(base_b + r16) * H_DIM + q4 * 8);
    const unsigned short* wslot = Wf + (size_t)(j >> 6) * 131072 + (size_t)(j & 63) * 8;

    f32x4 acc0 = {0.f, 0.f, 0.f, 0.f};
    f32x4 acc1 = {0.f, 0.f, 0.f, 0.f};
    #pragma unroll 8
    for (int kk = 0; kk < 32; ++kk) {
        bf16x8 a0 = Ap[kk * 4];
        bf16x8 a1 = Ap[kk * 4 + 128];
        bf16x8 b0 = *reinterpret_cast<const bf16x8*>(wslot + (size_t)(kk * 4 + q4) * 512);
        bf16x8 b1 = *reinterpret_cast<const bf16x8*>(wslot + (size_t)((kk + 32) * 4 + q4) * 512);
        acc0 = __builtin_amdgcn_mfma_f32_16x16x32_bf16(a0, b0, acc0, 0, 0, 0);
        acc1 = __builtin_amdgcn_mfma_f32_16x16x32_bf16(a1, b1, acc1, 0, 0, 0);
    }
    f32x4 h2h = acc0 + acc1;

    const float gamma = (j < N_HALF) ? -1.0f : 1.0f;
    const int brow0 = base_b + q4 * 4;
    #pragma unroll
    for (int i = 0; i < 4; ++i) {
        const int b = brow0 + i;
        const float v  = vel_t[b];
        const float hp = hprev[(size_t)b * H_DIM + j];
        const float pre = fmaf(v, gamma, 1.0f) + h2h[i];
        const float hn = OMA_F * hp + ALPHA_F * fmaxf(pre, 0.0f);
        acts_t[(size_t)b * H_DIM + j] = hn;
        hbf_out[(size_t)b * H_DIM + j] = f2bf(hn);
        if (outT) outT[(size_t)b * H_DIM + j] = hn;
    }
}

// ---------------------------------------------------------------------------
extern "C" void kernel_launch(void* const* d_in, const int* in_sizes, int n_in,
                              void* d_out, int out_size, void* d_ws, size_t ws_size,
                              hipStream_t stream) {
    const float* x       = (const float*)d_in[0];  // [T,B,IN]
    const float* hidden0 = (const float*)d_in[1];  // [B,H]
    const float* w_attr  = (const float*)d_in[2];  // [H,H]
    const float* w_in    = (const float*)d_in[3];  // [1,IN]

    float* acts = (float*)d_out;                               // [T,B,H]
    float* outT = acts + (size_t)T_STEPS * B_SZ * H_DIM;       // [B,H]

    unsigned char* ws = (unsigned char*)d_ws;
    unsigned short* Wf   = (unsigned short*)ws;                             // 8 MB
    unsigned short* hbf0 = (unsigned short*)(ws + ((size_t)8 << 20));       // 512 KB
    unsigned short* hbf1 = hbf0 + (size_t)B_SZ * H_DIM;                     // 512 KB
    float* vel = (float*)(ws + ((size_t)8 << 20) + (size_t)2 * B_SZ * H_DIM * 2); // 256 KB
    unsigned* bar = (unsigned*)(ws + ((size_t)8 << 20) + ((size_t)1 << 20) + (256 << 10)); // 4 KB

    hipMemsetAsync(bar, 0, 4096, stream);
    wf_kernel<<<dim3(32, 32), dim3(64, 4), 0, stream>>>(w_attr, Wf);
    vel_kernel<<<(T_STEPS * B_SZ + 255) / 256, 256, 0, stream>>>(x, w_in, vel);
    hbf_init_kernel<<<(B_SZ * H_DIM + 255) / 256, 256, 0, stream>>>(hidden0, hbf0);

    void* args[] = {(void*)&Wf, (void*)&hbf0, (void*)&hbf1, (void*)&vel,
                    (void*)&hidden0, (void*)&acts, (void*)&outT, (void*)&bar};
    hipError_t rc = hipLaunchCooperativeKernel(
        reinterpret_cast<void*>(ring_coop_kernel),
        dim3(256), dim3(512), args, 0, stream);

    if (rc != hipSuccess) {
        // fallback: per-step launches
        for (int t = 0; t < T_STEPS; ++t) {
            const unsigned short* hin = (t & 1) ? hbf1 : hbf0;
            unsigned short* hout      = (t & 1) ? hbf0 : hbf1;
            const float* hprev = (t == 0) ? hidden0 : acts + (size_t)(t - 1) * B_SZ * H_DIM;
            step_kernel<<<256, 256, 0, stream>>>(
                Wf, hin, hout, vel + (size_t)t * B_SZ, hprev,
                acts + (size_t)t * B_SZ * H_DIM,
                (t == T_STEPS - 1) ? outT : nullptr);
        }
    }
}

// Round 11
// 3048.363 us; speedup vs baseline: 4.0757x; 1.1983x over previous
//
#include <hip/hip_runtime.h>

#define H_DIM   2048
#define N_HALF  1024
#define B_SZ    128
#define T_STEPS 512
#define IN_DIM  64
#define ALPHA_F 0.05f
#define OMA_F   0.95f   // 1 - ALPHA

typedef __bf16 bf16x8 __attribute__((ext_vector_type(8)));
typedef float  f32x4  __attribute__((ext_vector_type(4)));
typedef unsigned int u32x4 __attribute__((ext_vector_type(4)));

// round-to-nearest-even f32 -> bf16 bits
__device__ __forceinline__ unsigned short f2bf(float f) {
    union { float f; unsigned int u; } v; v.f = f;
    unsigned int u = v.u;
    u += 0x7FFFu + ((u >> 16) & 1u);
    return (unsigned short)(u >> 16);
}

// ---------------------------------------------------------------------------
// Wf: weights in MFMA-fragment order:
//   Wf[(j>>6)*131072 + ((ks*4 + q4)*64 + (j&63))*8 + e] = bf16(W[k][j])
//   with ks = k>>5, q4 = (k>>3)&3, e = k&7.
// ---------------------------------------------------------------------------
__global__ void wf_kernel(const float* __restrict__ W, unsigned short* __restrict__ Wf) {
    __shared__ float tile[64][65];     // tile[kk][jj] = W[kb+kk][jb+jj]
    const int jb = blockIdx.x * 64;
    const int kb = blockIdx.y * 64;
    const int t  = threadIdx.y * 64 + threadIdx.x;   // 0..255
    const int tx = threadIdx.x, ty = threadIdx.y;
    #pragma unroll
    for (int r = ty; r < 64; r += 4)
        tile[r][tx] = W[(size_t)(kb + r) * H_DIM + jb + tx];
    __syncthreads();
    #pragma unroll
    for (int cc = 0; cc < 2; ++cc) {
        const int c  = t * 2 + cc;        // 0..511
        const int jj = c >> 3;            // 0..63
        const int kc = c & 7;             // 8-K group within tile
        const int j  = jb + jj;
        const int k0 = kb + kc * 8;
        unsigned short v[8];
        #pragma unroll
        for (int e = 0; e < 8; ++e)
            v[e] = f2bf(tile[kc * 8 + e][jj]);
        const int ks = k0 >> 5;
        const int q4 = (k0 >> 3) & 3;
        const size_t dst = (size_t)(j >> 6) * 131072 +
                           ((size_t)(ks * 4 + q4) * 64 + (j & 63)) * 8;
        *reinterpret_cast<u32x4*>(Wf + dst) = *reinterpret_cast<u32x4*>(v);
    }
}

// ---------------------------------------------------------------------------
__global__ void vel_kernel(const float* __restrict__ x, const float* __restrict__ w_in,
                           float* __restrict__ vel) {
    const int tb = blockIdx.x * blockDim.x + threadIdx.x;
    if (tb >= T_STEPS * B_SZ) return;
    const float* xp = x + (size_t)tb * IN_DIM;
    float s = 0.f;
    #pragma unroll
    for (int i = 0; i < IN_DIM; i += 4) {
        float4 xv = *reinterpret_cast<const float4*>(xp + i);
        float4 wv = *reinterpret_cast<const float4*>(w_in + i);
        s += xv.x * wv.x + xv.y * wv.y + xv.z * wv.z + xv.w * wv.w;
    }
    vel[tb] = s;
}

// ---------------------------------------------------------------------------
__global__ void hbf_init_kernel(const float* __restrict__ h0, unsigned short* __restrict__ hbf) {
    const int i = blockIdx.x * blockDim.x + threadIdx.x;
    hbf[i] = f2bf(h0[i]);
}

// ---------------------------------------------------------------------------
// Rowg-scoped two-level barrier: a block only needs its OWN rowg's 32
// producers (consumer reads h rows [rowg*16, rowg*16+16) only).
// Tree: 16-block subgroup counters (bid>>4) -> per-rowg root (2 incs) ->
// per-rowg generation word. Monotone counters, memset per launch.
// ---------------------------------------------------------------------------
__device__ __forceinline__ void ring_barrier(unsigned* bar, int t, int bid, int tid) {
    asm volatile("s_waitcnt vmcnt(0)" ::: "memory");  // h/acts stores complete
    __syncthreads();                                   // all waves drained
    if (tid == 0) {
        const int rowg = bid >> 5;
        unsigned* gcnt = bar + (bid >> 4) * 32;        // 16 subgroup counters
        unsigned* rcnt = bar + 512 + rowg * 32;        // per-rowg root
        unsigned* gen  = bar + 768 + rowg * 32;        // per-rowg generation
        unsigned old = __hip_atomic_fetch_add(gcnt, 1u, __ATOMIC_RELAXED,
                                              __HIP_MEMORY_SCOPE_AGENT);
        if (old == (unsigned)(t * 16 + 15)) {                 // last of subgroup
            unsigned r = __hip_atomic_fetch_add(rcnt, 1u, __ATOMIC_RELAXED,
                                                __HIP_MEMORY_SCOPE_AGENT);
            if (r == (unsigned)(t * 2 + 1)) {                 // both subgroups in
                __hip_atomic_store(gen, (unsigned)(t + 1), __ATOMIC_RELAXED,
                                   __HIP_MEMORY_SCOPE_AGENT);
            }
        }
        while (__hip_atomic_load(gen, __ATOMIC_RELAXED, __HIP_MEMORY_SCOPE_AGENT)
               < (unsigned)(t + 1)) {
            __builtin_amdgcn_s_sleep(1);
        }
    }
    __syncthreads();
}

// ---------------------------------------------------------------------------
// Persistent kernel: 256 blocks (1/CU) x 512 threads (8 waves).
// Block tile 16 rows x 64 cols; 8 waves = 4 col-quarters x 2 K-halves.
// A-panel (16x2048 bf16, 64 KB) staged to LDS per step via sc0+sc1 loads.
// LDS layout: 16B chunk c = kc*16 + row, XOR-swizzled c' with row bits 0..2
// ^= (kc>>2)&7 -> staging writes hit all 8 bank-groups evenly (was 32-way
// conflict, 4.8e8 counted); fragment reads stay structurally optimal.
// B streamed from Wf, CACHED (XCD-local L2-resident; no cache maintenance
// anywhere). h handoff sc0+sc1 both sides; acts nt; rowg-scoped barrier.
// ---------------------------------------------------------------------------
__global__ __launch_bounds__(512, 1) void ring_coop_kernel(
        const unsigned short* __restrict__ Wf,
        unsigned short* __restrict__ hbf0,
        unsigned short* __restrict__ hbf1,
        const float* __restrict__ vel,
        const float* __restrict__ hidden0,
        float* __restrict__ acts,
        float* __restrict__ outT,
        unsigned* __restrict__ bar) {
    __shared__ __align__(16) unsigned char A_lds[65536];   // swizzled frag chunks
    __shared__ __align__(16) f32x4 pacc[256];              // [colq][lane]
    __shared__ __align__(16) float hbuf[16][64];           // epilogue transpose

    const int tid = threadIdx.x;
    const int bid = blockIdx.x;
    // XCD swizzle (bid%8 = XCD): XCD x owns colgs {4x..4x+3} for ALL rowgs ->
    // B working set 1 MB per XCD, L2-resident across all 512 steps.
    const int colg = (bid & 7) * 4 + ((bid >> 3) & 3);   // 0..31 (64-col groups)
    const int rowg = bid >> 5;                            // 0..7  (16-row groups)
    const int colbase = colg * 64;
    const int rowbase = rowg * 16;

    const int lane = tid & 63, w = tid >> 6;   // 8 waves
    const int colq = w & 3, khalf = w >> 2;
    const int r16 = lane & 15, q4 = lane >> 4;
    const int j = colbase + colq * 16 + r16;
    const float gamma = (j < N_HALF) ? -1.0f : 1.0f;
    const unsigned short* wslot = Wf + (size_t)colg * 131072;

    // A-staging assignment: row = tid>>5 (32 threads/row), kb = tid&31
    const int srow = tid >> 5;
    const int kb   = tid & 31;
    // swizzled write base: chunk kb*16 + (srow ^ ((kb>>2)&7)), +i*512 chunks
    unsigned char* const ad0 = A_lds +
        ((size_t)(kb * 16 + (srow ^ ((kb >> 2) & 7))) * 16);

    // h_prev registers (khalf==0 waves): rows rowbase+q4*4+i, col j
    f32x4 hreg = {0.f, 0.f, 0.f, 0.f};
    if (khalf == 0) {
        #pragma unroll
        for (int i = 0; i < 4; ++i)
            hreg[i] = hidden0[(size_t)(rowbase + q4 * 4 + i) * H_DIM + j];
    }

    for (int t = 0; t < T_STEPS; ++t) {
        const unsigned short* hin  = (t & 1) ? hbf1 : hbf0;
        unsigned short*       hout = (t & 1) ? hbf0 : hbf1;
        const float* vel_t = vel + (size_t)t * B_SZ;
        float* acts_t = acts + (size_t)t * B_SZ * H_DIM;

        // ---- stage A panel (16 x 2048) to LDS, swizzled fragment order ----
        {
            const unsigned short* ap = hin + (size_t)(rowbase + srow) * H_DIM + kb * 8;
            u32x4 av0, av1, av2, av3, av4, av5, av6, av7;
            asm volatile("global_load_dwordx4 %0, %1, off sc0 sc1" : "=v"(av0) : "v"(ap));
            asm volatile("global_load_dwordx4 %0, %1, off sc0 sc1" : "=v"(av1) : "v"(ap + 256));
            asm volatile("global_load_dwordx4 %0, %1, off sc0 sc1" : "=v"(av2) : "v"(ap + 512));
            asm volatile("global_load_dwordx4 %0, %1, off sc0 sc1" : "=v"(av3) : "v"(ap + 768));
            asm volatile("global_load_dwordx4 %0, %1, off sc0 sc1" : "=v"(av4) : "v"(ap + 1024));
            asm volatile("global_load_dwordx4 %0, %1, off sc0 sc1" : "=v"(av5) : "v"(ap + 1280));
            asm volatile("global_load_dwordx4 %0, %1, off sc0 sc1" : "=v"(av6) : "v"(ap + 1536));
            asm volatile("global_load_dwordx4 %0, %1, off sc0 sc1" : "=v"(av7) : "v"(ap + 1792));
            asm volatile("s_waitcnt vmcnt(0)" ::: "memory");
            __builtin_amdgcn_sched_barrier(0);
            *reinterpret_cast<u32x4*>(ad0)            = av0;
            *reinterpret_cast<u32x4*>(ad0 + 8192)     = av1;
            *reinterpret_cast<u32x4*>(ad0 + 16384)    = av2;
            *reinterpret_cast<u32x4*>(ad0 + 24576)    = av3;
            *reinterpret_cast<u32x4*>(ad0 + 32768)    = av4;
            *reinterpret_cast<u32x4*>(ad0 + 40960)    = av5;
            *reinterpret_cast<u32x4*>(ad0 + 49152)    = av6;
            *reinterpret_cast<u32x4*>(ad0 + 57344)    = av7;
        }
        __syncthreads();

        // ---- GEMM: 32 MFMAs/wave (K-half), A from swizzled LDS, B from L2 ----
        const int abase_c = khalf * 2048 + q4 * 16;   // + s*64 + (r16 ^ (s&7))
        const unsigned short* bgbase = wslot + (size_t)(khalf * 128 + q4) * 512
                                       + (size_t)(colq * 16 + r16) * 8;
        f32x4 acc0 = {0.f,0.f,0.f,0.f}, acc1 = {0.f,0.f,0.f,0.f};
        f32x4 acc2 = {0.f,0.f,0.f,0.f}, acc3 = {0.f,0.f,0.f,0.f};
        #pragma unroll
        for (int s = 0; s < 32; s += 4) {
            bf16x8 b0 = *reinterpret_cast<const bf16x8*>(bgbase + (size_t)(s + 0) * 2048);
            bf16x8 b1 = *reinterpret_cast<const bf16x8*>(bgbase + (size_t)(s + 1) * 2048);
            bf16x8 b2 = *reinterpret_cast<const bf16x8*>(bgbase + (size_t)(s + 2) * 2048);
            bf16x8 b3 = *reinterpret_cast<const bf16x8*>(bgbase + (size_t)(s + 3) * 2048);
            bf16x8 a0 = *reinterpret_cast<const bf16x8*>(A_lds +
                (size_t)(abase_c + (s + 0) * 64 + (r16 ^ ((s + 0) & 7))) * 16);
            bf16x8 a1 = *reinterpret_cast<const bf16x8*>(A_lds +
                (size_t)(abase_c + (s + 1) * 64 + (r16 ^ ((s + 1) & 7))) * 16);
            bf16x8 a2 = *reinterpret_cast<const bf16x8*>(A_lds +
                (size_t)(abase_c + (s + 2) * 64 + (r16 ^ ((s + 2) & 7))) * 16);
            bf16x8 a3 = *reinterpret_cast<const bf16x8*>(A_lds +
                (size_t)(abase_c + (s + 3) * 64 + (r16 ^ ((s + 3) & 7))) * 16);
            acc0 = __builtin_amdgcn_mfma_f32_16x16x32_bf16(a0, b0, acc0, 0, 0, 0);
            acc1 = __builtin_amdgcn_mfma_f32_16x16x32_bf16(a1, b1, acc1, 0, 0, 0);
            acc2 = __builtin_amdgcn_mfma_f32_16x16x32_bf16(a2, b2, acc2, 0, 0, 0);
            acc3 = __builtin_amdgcn_mfma_f32_16x16x32_bf16(a3, b3, acc3, 0, 0, 0);
        }
        f32x4 psum = (acc0 + acc1) + (acc2 + acc3);

        // ---- K-pair reduce + epilogue into hbuf ----
        if (khalf == 1) pacc[colq * 64 + lane] = psum;
        __syncthreads();
        if (khalf == 0) {
            const f32x4 h2h = psum + pacc[colq * 64 + lane];
            const f32x4 vel4 = *reinterpret_cast<const f32x4*>(vel_t + rowbase + q4 * 4);
            #pragma unroll
            for (int i = 0; i < 4; ++i) {
                const float pre = fmaf(vel4[i], gamma, 1.0f) + h2h[i];
                const float hn = OMA_F * hreg[i] + ALPHA_F * fmaxf(pre, 0.0f);
                hreg[i] = hn;
                hbuf[q4 * 4 + i][colq * 16 + r16] = hn;
            }
        }
        __syncthreads();

        // ---- wide bypass stores from hbuf (split across waves) ----
        if (tid < 256) {                 // acts f32: 256 x 16B, nt
            const int row3 = tid >> 4, c4 = (tid & 15) * 4;
            f32x4 va = *reinterpret_cast<const f32x4*>(&hbuf[row3][c4]);
            float* dst = acts_t + (size_t)(rowbase + row3) * H_DIM + colbase + c4;
            asm volatile("global_store_dwordx4 %0, %1, off sc0 sc1 nt"
                         :: "v"(dst), "v"(va) : "memory");
        } else if (tid < 384) {          // h bf16: 128 x 16B, sc0 sc1
            const int t2 = tid - 256;
            const int row2 = t2 >> 3, c8 = (t2 & 7) * 8;
            unsigned pk[4];
            #pragma unroll
            for (int e = 0; e < 4; ++e)
                pk[e] = (unsigned)f2bf(hbuf[row2][c8 + 2 * e]) |
                        ((unsigned)f2bf(hbuf[row2][c8 + 2 * e + 1]) << 16);
            u32x4 hv = {pk[0], pk[1], pk[2], pk[3]};
            unsigned short* dst = hout + (size_t)(rowbase + row2) * H_DIM + colbase + c8;
            asm volatile("global_store_dwordx4 %0, %1, off sc0 sc1"
                         :: "v"(dst), "v"(hv) : "memory");
        } else if (t == T_STEPS - 1) {   // hT tail: 128 threads x 2 stores, plain
            #pragma unroll
            for (int e = 0; e < 2; ++e) {
                const int idx = (tid - 384) * 2 + e;
                const int row3 = idx >> 4, c4 = (idx & 15) * 4;
                f32x4 va = *reinterpret_cast<const f32x4*>(&hbuf[row3][c4]);
                *reinterpret_cast<f32x4*>(outT +
                    (size_t)(rowbase + row3) * H_DIM + colbase + c4) = va;
            }
        }

        if (t < T_STEPS - 1) ring_barrier(bar, t, bid, tid);
    }
}

// ---------------------------------------------------------------------------
// Fallback per-step kernel (Wf layout) if cooperative launch fails.
// ---------------------------------------------------------------------------
__global__ __launch_bounds__(256) void step_kernel(
        const unsigned short* __restrict__ Wf,
        const unsigned short* __restrict__ hbf_in,
        unsigned short* __restrict__ hbf_out,
        const float* __restrict__ vel_t,
        const float* __restrict__ hprev,
        float* __restrict__ acts_t,
        float* __restrict__ outT) {
    const int lane = threadIdx.x & 63;
    const int w    = threadIdx.x >> 6;
    const int bid  = blockIdx.x;
    const int mg   = bid >> 7;
    const int n    = bid & 127;
    const int base_b = mg * 64 + w * 16;
    const int base_j = n * 16;
    const int r16  = lane & 15;
    const int q4   = lane >> 4;

    const int j = base_j + r16;
    const bf16x8* Ap = reinterpret_cast<const bf16x8*>(
        hbf_in + (size_t)(base_b + r16) * H_DIM + q4 * 8);
    const unsigned short* wslot = Wf + (size_t)(j >> 6) * 131072 + (size_t)(j & 63) * 8;

    f32x4 acc0 = {0.f, 0.f, 0.f, 0.f};
    f32x4 acc1 = {0.f, 0.f, 0.f, 0.f};
    #pragma unroll 8
    for (int kk = 0; kk < 32; ++kk) {
        bf16x8 a0 = Ap[kk * 4];
        bf16x8 a1 = Ap[kk * 4 + 128];
        bf16x8 b0 = *reinterpret_cast<const bf16x8*>(wslot + (size_t)(kk * 4 + q4) * 512);
        bf16x8 b1 = *reinterpret_cast<const bf16x8*>(wslot + (size_t)((kk + 32) * 4 + q4) * 512);
        acc0 = __builtin_amdgcn_mfma_f32_16x16x32_bf16(a0, b0, acc0, 0, 0, 0);
        acc1 = __builtin_amdgcn_mfma_f32_16x16x32_bf16(a1, b1, acc1, 0, 0, 0);
    }
    f32x4 h2h = acc0 + acc1;

    const float gamma = (j < N_HALF) ? -1.0f : 1.0f;
    const int brow0 = base_b + q4 * 4;
    #pragma unroll
    for (int i = 0; i < 4; ++i) {
        const int b = brow0 + i;
        const float v  = vel_t[b];
        const float hp = hprev[(size_t)b * H_DIM + j];
        const float pre = fmaf(v, gamma, 1.0f) + h2h[i];
        const float hn = OMA_F * hp + ALPHA_F * fmaxf(pre, 0.0f);
        acts_t[(size_t)b * H_DIM + j] = hn;
        hbf_out[(size_t)b * H_DIM + j] = f2bf(hn);
        if (outT) outT[(size_t)b * H_DIM + j] = hn;
    }
}

// ---------------------------------------------------------------------------
extern "C" void kernel_launch(void* const* d_in, const int* in_sizes, int n_in,
                              void* d_out, int out_size, void* d_ws, size_t ws_size,
                              hipStream_t stream) {
    const float* x       = (const float*)d_in[0];  // [T,B,IN]
    const float* hidden0 = (const float*)d_in[1];  // [B,H]
    const float* w_attr  = (const float*)d_in[2];  // [H,H]
    const float* w_in    = (const float*)d_in[3];  // [1,IN]

    float* acts = (float*)d_out;                               // [T,B,H]
    float* outT = acts + (size_t)T_STEPS * B_SZ * H_DIM;       // [B,H]

    unsigned char* ws = (unsigned char*)d_ws;
    unsigned short* Wf   = (unsigned short*)ws;                             // 8 MB
    unsigned short* hbf0 = (unsigned short*)(ws + ((size_t)8 << 20));       // 512 KB
    unsigned short* hbf1 = hbf0 + (size_t)B_SZ * H_DIM;                     // 512 KB
    float* vel = (float*)(ws + ((size_t)8 << 20) + (size_t)2 * B_SZ * H_DIM * 2); // 256 KB
    unsigned* bar = (unsigned*)(ws + ((size_t)8 << 20) + ((size_t)1 << 20) + (256 << 10)); // 4 KB

    hipMemsetAsync(bar, 0, 4096, stream);
    wf_kernel<<<dim3(32, 32), dim3(64, 4), 0, stream>>>(w_attr, Wf);
    vel_kernel<<<(T_STEPS * B_SZ + 255) / 256, 256, 0, stream>>>(x, w_in, vel);
    hbf_init_kernel<<<(B_SZ * H_DIM + 255) / 256, 256, 0, stream>>>(hidden0, hbf0);

    void* args[] = {(void*)&Wf, (void*)&hbf0, (void*)&hbf1, (void*)&vel,
                    (void*)&hidden0, (void*)&acts, (void*)&outT, (void*)&bar};
    hipError_t rc = hipLaunchCooperativeKernel(
        reinterpret_cast<void*>(ring_coop_kernel),
        dim3(256), dim3(512), args, 0, stream);

    if (rc != hipSuccess) {
        // fallback: per-step launches
        for (int t = 0; t < T_STEPS; ++t) {
            const unsigned short* hin = (t & 1) ? hbf1 : hbf0;
            unsigned short* hout      = (t & 1) ? hbf0 : hbf1;
            const float* hprev = (t == 0) ? hidden0 : acts + (size_t)(t - 1) * B_SZ * H_DIM;
            step_kernel<<<256, 256, 0, stream>>>(
                Wf, hin, hout, vel + (size_t)t * B_SZ, hprev,
                acts + (size_t)t * B_SZ * H_DIM,
                (t == T_STEPS - 1) ? outT : nullptr);
        }
    }
}

// Round 12
// 2924.066 us; speedup vs baseline: 4.2490x; 1.0425x over previous
//
#include <hip/hip_runtime.h>

#define H_DIM   2048
#define N_HALF  1024
#define B_SZ    128
#define T_STEPS 512
#define IN_DIM  64
#define ALPHA_F 0.05f
#define OMA_F   0.95f   // 1 - ALPHA

typedef __bf16 bf16x8 __attribute__((ext_vector_type(8)));
typedef float  f32x4  __attribute__((ext_vector_type(4)));
typedef unsigned int u32x4 __attribute__((ext_vector_type(4)));

// round-to-nearest-even f32 -> bf16 bits
__device__ __forceinline__ unsigned short f2bf(float f) {
    union { float f; unsigned int u; } v; v.f = f;
    unsigned int u = v.u;
    u += 0x7FFFu + ((u >> 16) & 1u);
    return (unsigned short)(u >> 16);
}

// coherent 8B load (agent scope, cache-bypassing) — round-4-proven primitive
__device__ __forceinline__ unsigned long long ldA8(const unsigned long long* p) {
    return __hip_atomic_load(p, __ATOMIC_RELAXED, __HIP_MEMORY_SCOPE_AGENT);
}

// 1-lane-per-wave flag poll; compiler memory barrier on exit so staged data
// loads can't be hoisted above the observed flag.
__device__ __forceinline__ void pollflag(const unsigned* f, unsigned need, int lane) {
    if (lane == 0) {
        while (__hip_atomic_load(f, __ATOMIC_RELAXED, __HIP_MEMORY_SCOPE_AGENT) < need)
            __builtin_amdgcn_s_sleep(1);
    }
    asm volatile("" ::: "memory");
}

// ---------------------------------------------------------------------------
// Wf: weights in MFMA-fragment order:
//   Wf[(j>>6)*131072 + ((ks*4 + q4)*64 + (j&63))*8 + e] = bf16(W[k][j])
//   with ks = k>>5, q4 = (k>>3)&3, e = k&7.
// ---------------------------------------------------------------------------
__global__ void wf_kernel(const float* __restrict__ W, unsigned short* __restrict__ Wf) {
    __shared__ float tile[64][65];     // tile[kk][jj] = W[kb+kk][jb+jj]
    const int jb = blockIdx.x * 64;
    const int kb = blockIdx.y * 64;
    const int t  = threadIdx.y * 64 + threadIdx.x;   // 0..255
    const int tx = threadIdx.x, ty = threadIdx.y;
    #pragma unroll
    for (int r = ty; r < 64; r += 4)
        tile[r][tx] = W[(size_t)(kb + r) * H_DIM + jb + tx];
    __syncthreads();
    #pragma unroll
    for (int cc = 0; cc < 2; ++cc) {
        const int c  = t * 2 + cc;        // 0..511
        const int jj = c >> 3;            // 0..63
        const int kc = c & 7;             // 8-K group within tile
        const int j  = jb + jj;
        const int k0 = kb + kc * 8;
        unsigned short v[8];
        #pragma unroll
        for (int e = 0; e < 8; ++e)
            v[e] = f2bf(tile[kc * 8 + e][jj]);
        const int ks = k0 >> 5;
        const int q4 = (k0 >> 3) & 3;
        const size_t dst = (size_t)(j >> 6) * 131072 +
                           ((size_t)(ks * 4 + q4) * 64 + (j & 63)) * 8;
        *reinterpret_cast<u32x4*>(Wf + dst) = *reinterpret_cast<u32x4*>(v);
    }
}

// ---------------------------------------------------------------------------
__global__ void vel_kernel(const float* __restrict__ x, const float* __restrict__ w_in,
                           float* __restrict__ vel) {
    const int tb = blockIdx.x * blockDim.x + threadIdx.x;
    if (tb >= T_STEPS * B_SZ) return;
    const float* xp = x + (size_t)tb * IN_DIM;
    float s = 0.f;
    #pragma unroll
    for (int i = 0; i < IN_DIM; i += 4) {
        float4 xv = *reinterpret_cast<const float4*>(xp + i);
        float4 wv = *reinterpret_cast<const float4*>(w_in + i);
        s += xv.x * wv.x + xv.y * wv.y + xv.z * wv.z + xv.w * wv.w;
    }
    vel[tb] = s;
}

// ---------------------------------------------------------------------------
__global__ void hbf_init_kernel(const float* __restrict__ h0, unsigned short* __restrict__ hbf) {
    const int i = blockIdx.x * blockDim.x + threadIdx.x;
    hbf[i] = f2bf(h0[i]);
}

// ---------------------------------------------------------------------------
// Persistent kernel: 256 blocks (1/CU) x 512 threads (8 waves).
// Block tile 16 rows x 64 cols; 8 waves = 4 col-quarters x 2 K-halves.
// NO grid/rowg barrier: per-producer flags. Producer (rowg,cg) sets
// flag[rowg][cg]=t+1 after draining its h stores for step t. Consumer stages
// the 32 A K-chunks (2KB each) as their flags arrive — per wave 4 chunks in a
// depth-2 pipeline (poll chunk i+1 while chunk i loads are in flight).
// Safety: a block reaches step t+1's h stores only after ALL rowg flags >= t+1,
// i.e. every peer finished reading gen-t — double-buffer overwrite is safe.
// LDS chunk swizzle row^kcl: staging writes and fragment reads both hit all 8
// bank groups evenly (structural optimum for b128).
// B streamed from Wf, CACHED (XCD-local L2-resident, bid%8 col partition).
// h handoff sc0+sc1 both sides; acts nt; h_prev in registers.
// ---------------------------------------------------------------------------
__global__ __launch_bounds__(512, 1) void ring_coop_kernel(
        const unsigned short* __restrict__ Wf,
        unsigned short* __restrict__ hbf0,
        unsigned short* __restrict__ hbf1,
        const float* __restrict__ vel,
        const float* __restrict__ hidden0,
        float* __restrict__ acts,
        float* __restrict__ outT,
        unsigned* __restrict__ flags) {
    __shared__ __align__(16) unsigned char A_lds[65536];   // swizzled frag chunks
    __shared__ __align__(16) f32x4 pacc[256];              // [colq][lane]
    __shared__ __align__(16) float hbuf[16][64];           // epilogue transpose

    const int tid = threadIdx.x;
    const int bid = blockIdx.x;
    // XCD swizzle (bid%8 = XCD): XCD x owns colgs {4x..4x+3} for ALL rowgs ->
    // B working set 1 MB per XCD, L2-resident across all 512 steps.
    const int colg = (bid & 7) * 4 + ((bid >> 3) & 3);   // 0..31 (64-col groups)
    const int rowg = bid >> 5;                            // 0..7  (16-row groups)
    const int colbase = colg * 64;
    const int rowbase = rowg * 16;

    const int lane = tid & 63, w = tid >> 6;   // 8 waves
    const int colq = w & 3, khalf = w >> 2;
    const int r16 = lane & 15, q4 = lane >> 4;
    const int j = colbase + colq * 16 + r16;
    const float gamma = (j < N_HALF) ? -1.0f : 1.0f;
    const unsigned short* wslot = Wf + (size_t)colg * 131072;

    // staging lane identity: rows srow / srow+8, K-subchunk kcl (8 K each)
    const int srow = lane >> 3;      // 0..7
    const int kcl  = lane & 7;       // 0..7

    unsigned* rflags = flags + rowg * 128;    // flag for cg at rflags[cg*4]

    // h_prev registers (khalf==0 waves): rows rowbase+q4*4+i, col j
    f32x4 hreg = {0.f, 0.f, 0.f, 0.f};
    if (khalf == 0) {
        #pragma unroll
        for (int i = 0; i < 4; ++i)
            hreg[i] = hidden0[(size_t)(rowbase + q4 * 4 + i) * H_DIM + j];
    }

    const int xe = r16 ^ q4;     // read swizzle, even s
    const int xo = xe ^ 4;       // read swizzle, odd  s

    for (int t = 0; t < T_STEPS; ++t) {
        const unsigned short* hin  = (t & 1) ? hbf1 : hbf0;
        unsigned short*       hout = (t & 1) ? hbf0 : hbf1;
        const float* vel_t = vel + (size_t)t * B_SZ;
        float* acts_t = acts + (size_t)t * B_SZ * H_DIM;

        // ---- pipelined staging: 4 chunks/wave, poll overlapped with loads ----
        {
            int cg = (colg + 1 + w) & 31;
            pollflag(rflags + cg * 4, (unsigned)t, lane);
            const unsigned long long* ap = reinterpret_cast<const unsigned long long*>(
                hin + (size_t)(rowbase + srow) * H_DIM + cg * 64 + kcl * 8);
            unsigned long long p0 = ldA8(ap), p1 = ldA8(ap + 1);
            unsigned long long p2 = ldA8(ap + 4096), p3 = ldA8(ap + 4097);
            #pragma unroll
            for (int i = 0; i < 4; ++i) {
                unsigned long long n0 = 0, n1 = 0, n2 = 0, n3 = 0;
                int cgn = 0;
                if (i < 3) {
                    cgn = (colg + 1 + w + 8 * (i + 1)) & 31;
                    pollflag(rflags + cgn * 4, (unsigned)t, lane);
                    const unsigned long long* apn = reinterpret_cast<const unsigned long long*>(
                        hin + (size_t)(rowbase + srow) * H_DIM + cgn * 64 + kcl * 8);
                    n0 = ldA8(apn); n1 = ldA8(apn + 1);
                    n2 = ldA8(apn + 4096); n3 = ldA8(apn + 4097);
                }
                union { unsigned long long u[2]; u32x4 v; } lo, hi;
                lo.u[0] = p0; lo.u[1] = p1; hi.u[0] = p2; hi.u[1] = p3;
                *reinterpret_cast<u32x4*>(A_lds +
                    (size_t)((cg * 8 + kcl) * 16 + (srow ^ kcl)) * 16) = lo.v;
                *reinterpret_cast<u32x4*>(A_lds +
                    (size_t)((cg * 8 + kcl) * 16 + ((srow + 8) ^ kcl)) * 16) = hi.v;
                if (i < 3) { p0 = n0; p1 = n1; p2 = n2; p3 = n3; cg = cgn; }
            }
        }
        __syncthreads();

        // ---- GEMM: 32 MFMAs/wave (K-half), A from swizzled LDS, B from L2 ----
        const unsigned char* Abase = A_lds + (size_t)(khalf * 2048 + q4 * 16) * 16;
        const unsigned short* bgbase = wslot + (size_t)(khalf * 128 + q4) * 512
                                       + (size_t)(colq * 16 + r16) * 8;
        f32x4 acc0 = {0.f,0.f,0.f,0.f}, acc1 = {0.f,0.f,0.f,0.f};
        f32x4 acc2 = {0.f,0.f,0.f,0.f}, acc3 = {0.f,0.f,0.f,0.f};
        #pragma unroll
        for (int s = 0; s < 32; s += 4) {
            bf16x8 b0 = *reinterpret_cast<const bf16x8*>(bgbase + (size_t)(s + 0) * 2048);
            bf16x8 b1 = *reinterpret_cast<const bf16x8*>(bgbase + (size_t)(s + 1) * 2048);
            bf16x8 b2 = *reinterpret_cast<const bf16x8*>(bgbase + (size_t)(s + 2) * 2048);
            bf16x8 b3 = *reinterpret_cast<const bf16x8*>(bgbase + (size_t)(s + 3) * 2048);
            bf16x8 a0 = *reinterpret_cast<const bf16x8*>(Abase +
                (size_t)((s + 0) * 64 + xe) * 16);
            bf16x8 a1 = *reinterpret_cast<const bf16x8*>(Abase +
                (size_t)((s + 1) * 64 + xo) * 16);
            bf16x8 a2 = *reinterpret_cast<const bf16x8*>(Abase +
                (size_t)((s + 2) * 64 + xe) * 16);
            bf16x8 a3 = *reinterpret_cast<const bf16x8*>(Abase +
                (size_t)((s + 3) * 64 + xo) * 16);
            acc0 = __builtin_amdgcn_mfma_f32_16x16x32_bf16(a0, b0, acc0, 0, 0, 0);
            acc1 = __builtin_amdgcn_mfma_f32_16x16x32_bf16(a1, b1, acc1, 0, 0, 0);
            acc2 = __builtin_amdgcn_mfma_f32_16x16x32_bf16(a2, b2, acc2, 0, 0, 0);
            acc3 = __builtin_amdgcn_mfma_f32_16x16x32_bf16(a3, b3, acc3, 0, 0, 0);
        }
        f32x4 psum = (acc0 + acc1) + (acc2 + acc3);

        // ---- K-pair reduce + epilogue into hbuf ----
        if (khalf == 1) pacc[colq * 64 + lane] = psum;
        __syncthreads();
        if (khalf == 0) {
            const f32x4 h2h = psum + pacc[colq * 64 + lane];
            const f32x4 vel4 = *reinterpret_cast<const f32x4*>(vel_t + rowbase + q4 * 4);
            #pragma unroll
            for (int i = 0; i < 4; ++i) {
                const float pre = fmaf(vel4[i], gamma, 1.0f) + h2h[i];
                const float hn = OMA_F * hreg[i] + ALPHA_F * fmaxf(pre, 0.0f);
                hreg[i] = hn;
                hbuf[q4 * 4 + i][colq * 16 + r16] = hn;
            }
        }
        __syncthreads();

        // ---- wide bypass stores from hbuf (split across waves) ----
        if (tid < 256) {                 // acts f32: 256 x 16B, nt (no drain req)
            const int row3 = tid >> 4, c4 = (tid & 15) * 4;
            f32x4 va = *reinterpret_cast<const f32x4*>(&hbuf[row3][c4]);
            float* dst = acts_t + (size_t)(rowbase + row3) * H_DIM + colbase + c4;
            asm volatile("global_store_dwordx4 %0, %1, off sc0 sc1 nt"
                         :: "v"(dst), "v"(va) : "memory");
        } else if (tid < 384) {          // h bf16: 128 x 16B, sc0 sc1 + drain
            const int t2 = tid - 256;
            const int row2 = t2 >> 3, c8 = (t2 & 7) * 8;
            unsigned pk[4];
            #pragma unroll
            for (int e = 0; e < 4; ++e)
                pk[e] = (unsigned)f2bf(hbuf[row2][c8 + 2 * e]) |
                        ((unsigned)f2bf(hbuf[row2][c8 + 2 * e + 1]) << 16);
            u32x4 hv = {pk[0], pk[1], pk[2], pk[3]};
            unsigned short* dst = hout + (size_t)(rowbase + row2) * H_DIM + colbase + c8;
            asm volatile("global_store_dwordx4 %0, %1, off sc0 sc1"
                         :: "v"(dst), "v"(hv) : "memory");
            asm volatile("s_waitcnt vmcnt(0)" ::: "memory");
        } else if (t == T_STEPS - 1) {   // hT tail: 128 threads x 2 stores, plain
            #pragma unroll
            for (int e = 0; e < 2; ++e) {
                const int idx = (tid - 384) * 2 + e;
                const int row3 = idx >> 4, c4 = (idx & 15) * 4;
                f32x4 va = *reinterpret_cast<const f32x4*>(&hbuf[row3][c4]);
                *reinterpret_cast<f32x4*>(outT +
                    (size_t)(rowbase + row3) * H_DIM + colbase + c4) = va;
            }
        }
        __syncthreads();                 // h stores of all producers drained
        if (tid == 0 && t < T_STEPS - 1)
            __hip_atomic_store(rflags + colg * 4, (unsigned)(t + 1),
                               __ATOMIC_RELAXED, __HIP_MEMORY_SCOPE_AGENT);
    }
}

// ---------------------------------------------------------------------------
// Fallback per-step kernel (Wf layout) if cooperative launch fails.
// ---------------------------------------------------------------------------
__global__ __launch_bounds__(256) void step_kernel(
        const unsigned short* __restrict__ Wf,
        const unsigned short* __restrict__ hbf_in,
        unsigned short* __restrict__ hbf_out,
        const float* __restrict__ vel_t,
        const float* __restrict__ hprev,
        float* __restrict__ acts_t,
        float* __restrict__ outT) {
    const int lane = threadIdx.x & 63;
    const int w    = threadIdx.x >> 6;
    const int bid  = blockIdx.x;
    const int mg   = bid >> 7;
    const int n    = bid & 127;
    const int base_b = mg * 64 + w * 16;
    const int base_j = n * 16;
    const int r16  = lane & 15;
    const int q4   = lane >> 4;

    const int j = base_j + r16;
    const bf16x8* Ap = reinterpret_cast<const bf16x8*>(
        hbf_in + (size_t)(base_b + r16) * H_DIM + q4 * 8);
    const unsigned short* wslot = Wf + (size_t)(j >> 6) * 131072 + (size_t)(j & 63) * 8;

    f32x4 acc0 = {0.f, 0.f, 0.f, 0.f};
    f32x4 acc1 = {0.f, 0.f, 0.f, 0.f};
    #pragma unroll 8
    for (int kk = 0; kk < 32; ++kk) {
        bf16x8 a0 = Ap[kk * 4];
        bf16x8 a1 = Ap[kk * 4 + 128];
        bf16x8 b0 = *reinterpret_cast<const bf16x8*>(wslot + (size_t)(kk * 4 + q4) * 512);
        bf16x8 b1 = *reinterpret_cast<const bf16x8*>(wslot + (size_t)((kk + 32) * 4 + q4) * 512);
        acc0 = __builtin_amdgcn_mfma_f32_16x16x32_bf16(a0, b0, acc0, 0, 0, 0);
        acc1 = __builtin_amdgcn_mfma_f32_16x16x32_bf16(a1, b1, acc1, 0, 0, 0);
    }
    f32x4 h2h = acc0 + acc1;

    const float gamma = (j < N_HALF) ? -1.0f : 1.0f;
    const int brow0 = base_b + q4 * 4;
    #pragma unroll
    for (int i = 0; i < 4; ++i) {
        const int b = brow0 + i;
        const float v  = vel_t[b];
        const float hp = hprev[(size_t)b * H_DIM + j];
        const float pre = fmaf(v, gamma, 1.0f) + h2h[i];
        const float hn = OMA_F * hp + ALPHA_F * fmaxf(pre, 0.0f);
        acts_t[(size_t)b * H_DIM + j] = hn;
        hbf_out[(size_t)b * H_DIM + j] = f2bf(hn);
        if (outT) outT[(size_t)b * H_DIM + j] = hn;
    }
}

// ---------------------------------------------------------------------------
extern "C" void kernel_launch(void* const* d_in, const int* in_sizes, int n_in,
                              void* d_out, int out_size, void* d_ws, size_t ws_size,
                              hipStream_t stream) {
    const float* x       = (const float*)d_in[0];  // [T,B,IN]
    const float* hidden0 = (const float*)d_in[1];  // [B,H]
    const float* w_attr  = (const float*)d_in[2];  // [H,H]
    const float* w_in    = (const float*)d_in[3];  // [1,IN]

    float* acts = (float*)d_out;                               // [T,B,H]
    float* outT = acts + (size_t)T_STEPS * B_SZ * H_DIM;       // [B,H]

    unsigned char* ws = (unsigned char*)d_ws;
    unsigned short* Wf   = (unsigned short*)ws;                             // 8 MB
    unsigned short* hbf0 = (unsigned short*)(ws + ((size_t)8 << 20));       // 512 KB
    unsigned short* hbf1 = hbf0 + (size_t)B_SZ * H_DIM;                     // 512 KB
    float* vel = (float*)(ws + ((size_t)8 << 20) + (size_t)2 * B_SZ * H_DIM * 2); // 256 KB
    unsigned* flags = (unsigned*)(ws + ((size_t)8 << 20) + ((size_t)1 << 20) + (256 << 10)); // 4 KB

    hipMemsetAsync(flags, 0, 4096, stream);
    wf_kernel<<<dim3(32, 32), dim3(64, 4), 0, stream>>>(w_attr, Wf);
    vel_kernel<<<(T_STEPS * B_SZ + 255) / 256, 256, 0, stream>>>(x, w_in, vel);
    hbf_init_kernel<<<(B_SZ * H_DIM + 255) / 256, 256, 0, stream>>>(hidden0, hbf0);

    void* args[] = {(void*)&Wf, (void*)&hbf0, (void*)&hbf1, (void*)&vel,
                    (void*)&hidden0, (void*)&acts, (void*)&outT, (void*)&flags};
    hipError_t rc = hipLaunchCooperativeKernel(
        reinterpret_cast<void*>(ring_coop_kernel),
        dim3(256), dim3(512), args, 0, stream);

    if (rc != hipSuccess) {
        // fallback: per-step launches
        for (int t = 0; t < T_STEPS; ++t) {
            const unsigned short* hin = (t & 1) ? hbf1 : hbf0;
            unsigned short* hout      = (t & 1) ? hbf0 : hbf1;
            const float* hprev = (t == 0) ? hidden0 : acts + (size_t)(t - 1) * B_SZ * H_DIM;
            step_kernel<<<256, 256, 0, stream>>>(
                Wf, hin, hout, vel + (size_t)t * B_SZ, hprev,
                acts + (size_t)t * B_SZ * H_DIM,
                (t == T_STEPS - 1) ? outT : nullptr);
        }
    }
}

// Round 13
// 2179.788 us; speedup vs baseline: 5.6998x; 1.3414x over previous
//
#include <hip/hip_runtime.h>

#define H_DIM   2048
#define N_HALF  1024
#define B_SZ    128
#define T_STEPS 512
#define IN_DIM  64
#define ALPHA_F 0.05f
#define OMA_F   0.95f   // 1 - ALPHA

typedef __bf16 bf16x8 __attribute__((ext_vector_type(8)));
typedef float  f32x4  __attribute__((ext_vector_type(4)));
typedef unsigned int u32x4 __attribute__((ext_vector_type(4)));

// round-to-nearest-even f32 -> bf16 bits
__device__ __forceinline__ unsigned short f2bf(float f) {
    union { float f; unsigned int u; } v; v.f = f;
    unsigned int u = v.u;
    u += 0x7FFFu + ((u >> 16) & 1u);
    return (unsigned short)(u >> 16);
}

// coherent 8B load (agent scope, cache-bypassing) — round-4-proven primitive
__device__ __forceinline__ unsigned long long ldA8(const unsigned long long* p) {
    return __hip_atomic_load(p, __ATOMIC_RELAXED, __HIP_MEMORY_SCOPE_AGENT);
}

// 1-lane-per-wave flag poll; compiler memory barrier on exit so staged data
// loads can't be hoisted above the observed flag.
__device__ __forceinline__ void pollflag(const unsigned* f, unsigned need, int lane) {
    if (lane == 0) {
        while (__hip_atomic_load(f, __ATOMIC_RELAXED, __HIP_MEMORY_SCOPE_AGENT) < need)
            __builtin_amdgcn_s_sleep(1);
    }
    asm volatile("" ::: "memory");
}

// ---------------------------------------------------------------------------
// Wf: weights in MFMA-fragment order:
//   Wf[(j>>6)*131072 + ((ks*4 + q4)*64 + (j&63))*8 + e] = bf16(W[k][j])
//   with ks = k>>5, q4 = (k>>3)&3, e = k&7.
// ---------------------------------------------------------------------------
__global__ void wf_kernel(const float* __restrict__ W, unsigned short* __restrict__ Wf) {
    __shared__ float tile[64][65];     // tile[kk][jj] = W[kb+kk][jb+jj]
    const int jb = blockIdx.x * 64;
    const int kb = blockIdx.y * 64;
    const int t  = threadIdx.y * 64 + threadIdx.x;   // 0..255
    const int tx = threadIdx.x, ty = threadIdx.y;
    #pragma unroll
    for (int r = ty; r < 64; r += 4)
        tile[r][tx] = W[(size_t)(kb + r) * H_DIM + jb + tx];
    __syncthreads();
    #pragma unroll
    for (int cc = 0; cc < 2; ++cc) {
        const int c  = t * 2 + cc;        // 0..511
        const int jj = c >> 3;            // 0..63
        const int kc = c & 7;             // 8-K group within tile
        const int j  = jb + jj;
        const int k0 = kb + kc * 8;
        unsigned short v[8];
        #pragma unroll
        for (int e = 0; e < 8; ++e)
            v[e] = f2bf(tile[kc * 8 + e][jj]);
        const int ks = k0 >> 5;
        const int q4 = (k0 >> 3) & 3;
        const size_t dst = (size_t)(j >> 6) * 131072 +
                           ((size_t)(ks * 4 + q4) * 64 + (j & 63)) * 8;
        *reinterpret_cast<u32x4*>(Wf + dst) = *reinterpret_cast<u32x4*>(v);
    }
}

// ---------------------------------------------------------------------------
__global__ void vel_kernel(const float* __restrict__ x, const float* __restrict__ w_in,
                           float* __restrict__ vel) {
    const int tb = blockIdx.x * blockDim.x + threadIdx.x;
    if (tb >= T_STEPS * B_SZ) return;
    const float* xp = x + (size_t)tb * IN_DIM;
    float s = 0.f;
    #pragma unroll
    for (int i = 0; i < IN_DIM; i += 4) {
        float4 xv = *reinterpret_cast<const float4*>(xp + i);
        float4 wv = *reinterpret_cast<const float4*>(w_in + i);
        s += xv.x * wv.x + xv.y * wv.y + xv.z * wv.z + xv.w * wv.w;
    }
    vel[tb] = s;
}

// ---------------------------------------------------------------------------
__global__ void hbf_init_kernel(const float* __restrict__ h0, unsigned short* __restrict__ hbf) {
    const int i = blockIdx.x * blockDim.x + threadIdx.x;
    hbf[i] = f2bf(h0[i]);
}

// ---------------------------------------------------------------------------
// Persistent kernel: 256 blocks (1/CU) x 512 threads (8 waves).
// Block tile 16 rows x 64 cols; 8 waves = 4 col-quarters x 2 K-halves.
// NEW (r13): each wave holds its ENTIRE B working set in registers —
// Breg[32] = 32 fragments x 16B = 128 VGPRs, loaded ONCE before the t-loop
// (W is constant). The in-loop GEMM is LDS-A ds_read_b128 + register-B MFMA:
// zero B memory traffic per step (was 256KB/block/step from L2).
// Sync: per-producer flags; consumer stages 32 A K-chunks (2KB each) as
// flags arrive, depth-2 pipelined, LDS chunk swizzle row^kcl (conflict-free).
// h handoff sc0+sc1 both sides; acts nt; h_prev in registers.
// ---------------------------------------------------------------------------
__global__ __launch_bounds__(512, 1) void ring_coop_kernel(
        const unsigned short* __restrict__ Wf,
        unsigned short* __restrict__ hbf0,
        unsigned short* __restrict__ hbf1,
        const float* __restrict__ vel,
        const float* __restrict__ hidden0,
        float* __restrict__ acts,
        float* __restrict__ outT,
        unsigned* __restrict__ flags) {
    __shared__ __align__(16) unsigned char A_lds[65536];   // swizzled frag chunks
    __shared__ __align__(16) f32x4 pacc[256];              // [colq][lane]
    __shared__ __align__(16) float hbuf[16][64];           // epilogue transpose

    const int tid = threadIdx.x;
    const int bid = blockIdx.x;
    // XCD swizzle (bid%8 = XCD): XCD x owns colgs {4x..4x+3} for ALL rowgs.
    const int colg = (bid & 7) * 4 + ((bid >> 3) & 3);   // 0..31 (64-col groups)
    const int rowg = bid >> 5;                            // 0..7  (16-row groups)
    const int colbase = colg * 64;
    const int rowbase = rowg * 16;

    const int lane = tid & 63, w = tid >> 6;   // 8 waves
    const int colq = w & 3, khalf = w >> 2;
    const int r16 = lane & 15, q4 = lane >> 4;
    const int j = colbase + colq * 16 + r16;
    const float gamma = (j < N_HALF) ? -1.0f : 1.0f;

    // staging lane identity: rows srow / srow+8, K-subchunk kcl (8 K each)
    const int srow = lane >> 3;      // 0..7
    const int kcl  = lane & 7;       // 0..7

    unsigned* rflags = flags + rowg * 128;    // flag for cg at rflags[cg*4]

    // ---- one-time: B fragments into registers (W constant across steps) ----
    const unsigned short* bgbase = Wf + (size_t)colg * 131072
                                   + (size_t)(khalf * 128 + q4) * 512
                                   + (size_t)(colq * 16 + r16) * 8;
    bf16x8 Breg[32];
    #pragma unroll
    for (int s = 0; s < 32; ++s)
        Breg[s] = *reinterpret_cast<const bf16x8*>(bgbase + (size_t)s * 2048);

    // h_prev registers (khalf==0 waves): rows rowbase+q4*4+i, col j
    f32x4 hreg = {0.f, 0.f, 0.f, 0.f};
    if (khalf == 0) {
        #pragma unroll
        for (int i = 0; i < 4; ++i)
            hreg[i] = hidden0[(size_t)(rowbase + q4 * 4 + i) * H_DIM + j];
    }

    const int xe = r16 ^ q4;     // read swizzle, even s
    const int xo = xe ^ 4;       // read swizzle, odd  s

    for (int t = 0; t < T_STEPS; ++t) {
        const unsigned short* hin  = (t & 1) ? hbf1 : hbf0;
        unsigned short*       hout = (t & 1) ? hbf0 : hbf1;
        const float* vel_t = vel + (size_t)t * B_SZ;
        float* acts_t = acts + (size_t)t * B_SZ * H_DIM;

        // ---- pipelined staging: 4 chunks/wave, poll overlapped with loads ----
        {
            int cg = (colg + 1 + w) & 31;
            pollflag(rflags + cg * 4, (unsigned)t, lane);
            const unsigned long long* ap = reinterpret_cast<const unsigned long long*>(
                hin + (size_t)(rowbase + srow) * H_DIM + cg * 64 + kcl * 8);
            unsigned long long p0 = ldA8(ap), p1 = ldA8(ap + 1);
            unsigned long long p2 = ldA8(ap + 4096), p3 = ldA8(ap + 4097);
            #pragma unroll
            for (int i = 0; i < 4; ++i) {
                unsigned long long n0 = 0, n1 = 0, n2 = 0, n3 = 0;
                int cgn = 0;
                if (i < 3) {
                    cgn = (colg + 1 + w + 8 * (i + 1)) & 31;
                    pollflag(rflags + cgn * 4, (unsigned)t, lane);
                    const unsigned long long* apn = reinterpret_cast<const unsigned long long*>(
                        hin + (size_t)(rowbase + srow) * H_DIM + cgn * 64 + kcl * 8);
                    n0 = ldA8(apn); n1 = ldA8(apn + 1);
                    n2 = ldA8(apn + 4096); n3 = ldA8(apn + 4097);
                }
                union { unsigned long long u[2]; u32x4 v; } lo, hi;
                lo.u[0] = p0; lo.u[1] = p1; hi.u[0] = p2; hi.u[1] = p3;
                *reinterpret_cast<u32x4*>(A_lds +
                    (size_t)((cg * 8 + kcl) * 16 + (srow ^ kcl)) * 16) = lo.v;
                *reinterpret_cast<u32x4*>(A_lds +
                    (size_t)((cg * 8 + kcl) * 16 + ((srow + 8) ^ kcl)) * 16) = hi.v;
                if (i < 3) { p0 = n0; p1 = n1; p2 = n2; p3 = n3; cg = cgn; }
            }
        }
        __syncthreads();

        // ---- GEMM: 32 MFMAs/wave, A from swizzled LDS, B from REGISTERS ----
        const unsigned char* Abase = A_lds + (size_t)(khalf * 2048 + q4 * 16) * 16;
        f32x4 acc0 = {0.f,0.f,0.f,0.f}, acc1 = {0.f,0.f,0.f,0.f};
        f32x4 acc2 = {0.f,0.f,0.f,0.f}, acc3 = {0.f,0.f,0.f,0.f};
        #pragma unroll
        for (int s = 0; s < 32; s += 4) {
            bf16x8 a0 = *reinterpret_cast<const bf16x8*>(Abase +
                (size_t)((s + 0) * 64 + xe) * 16);
            bf16x8 a1 = *reinterpret_cast<const bf16x8*>(Abase +
                (size_t)((s + 1) * 64 + xo) * 16);
            bf16x8 a2 = *reinterpret_cast<const bf16x8*>(Abase +
                (size_t)((s + 2) * 64 + xe) * 16);
            bf16x8 a3 = *reinterpret_cast<const bf16x8*>(Abase +
                (size_t)((s + 3) * 64 + xo) * 16);
            acc0 = __builtin_amdgcn_mfma_f32_16x16x32_bf16(a0, Breg[s + 0], acc0, 0, 0, 0);
            acc1 = __builtin_amdgcn_mfma_f32_16x16x32_bf16(a1, Breg[s + 1], acc1, 0, 0, 0);
            acc2 = __builtin_amdgcn_mfma_f32_16x16x32_bf16(a2, Breg[s + 2], acc2, 0, 0, 0);
            acc3 = __builtin_amdgcn_mfma_f32_16x16x32_bf16(a3, Breg[s + 3], acc3, 0, 0, 0);
        }
        f32x4 psum = (acc0 + acc1) + (acc2 + acc3);

        // ---- K-pair reduce + epilogue into hbuf ----
        if (khalf == 1) pacc[colq * 64 + lane] = psum;
        __syncthreads();
        if (khalf == 0) {
            const f32x4 h2h = psum + pacc[colq * 64 + lane];
            const f32x4 vel4 = *reinterpret_cast<const f32x4*>(vel_t + rowbase + q4 * 4);
            #pragma unroll
            for (int i = 0; i < 4; ++i) {
                const float pre = fmaf(vel4[i], gamma, 1.0f) + h2h[i];
                const float hn = OMA_F * hreg[i] + ALPHA_F * fmaxf(pre, 0.0f);
                hreg[i] = hn;
                hbuf[q4 * 4 + i][colq * 16 + r16] = hn;
            }
        }
        __syncthreads();

        // ---- wide bypass stores from hbuf (split across waves) ----
        if (tid < 256) {                 // acts f32: 256 x 16B, nt (no drain req)
            const int row3 = tid >> 4, c4 = (tid & 15) * 4;
            f32x4 va = *reinterpret_cast<const f32x4*>(&hbuf[row3][c4]);
            float* dst = acts_t + (size_t)(rowbase + row3) * H_DIM + colbase + c4;
            asm volatile("global_store_dwordx4 %0, %1, off sc0 sc1 nt"
                         :: "v"(dst), "v"(va) : "memory");
        } else if (tid < 384) {          // h bf16: 128 x 16B, sc0 sc1 + drain
            const int t2 = tid - 256;
            const int row2 = t2 >> 3, c8 = (t2 & 7) * 8;
            unsigned pk[4];
            #pragma unroll
            for (int e = 0; e < 4; ++e)
                pk[e] = (unsigned)f2bf(hbuf[row2][c8 + 2 * e]) |
                        ((unsigned)f2bf(hbuf[row2][c8 + 2 * e + 1]) << 16);
            u32x4 hv = {pk[0], pk[1], pk[2], pk[3]};
            unsigned short* dst = hout + (size_t)(rowbase + row2) * H_DIM + colbase + c8;
            asm volatile("global_store_dwordx4 %0, %1, off sc0 sc1"
                         :: "v"(dst), "v"(hv) : "memory");
            asm volatile("s_waitcnt vmcnt(0)" ::: "memory");
        } else if (t == T_STEPS - 1) {   // hT tail: 128 threads x 2 stores, plain
            #pragma unroll
            for (int e = 0; e < 2; ++e) {
                const int idx = (tid - 384) * 2 + e;
                const int row3 = idx >> 4, c4 = (idx & 15) * 4;
                f32x4 va = *reinterpret_cast<const f32x4*>(&hbuf[row3][c4]);
                *reinterpret_cast<f32x4*>(outT +
                    (size_t)(rowbase + row3) * H_DIM + colbase + c4) = va;
            }
        }
        __syncthreads();                 // h stores of all producers drained
        if (tid == 0 && t < T_STEPS - 1)
            __hip_atomic_store(rflags + colg * 4, (unsigned)(t + 1),
                               __ATOMIC_RELAXED, __HIP_MEMORY_SCOPE_AGENT);
    }
}

// ---------------------------------------------------------------------------
// Fallback per-step kernel (Wf layout) if cooperative launch fails.
// ---------------------------------------------------------------------------
__global__ __launch_bounds__(256) void step_kernel(
        const unsigned short* __restrict__ Wf,
        const unsigned short* __restrict__ hbf_in,
        unsigned short* __restrict__ hbf_out,
        const float* __restrict__ vel_t,
        const float* __restrict__ hprev,
        float* __restrict__ acts_t,
        float* __restrict__ outT) {
    const int lane = threadIdx.x & 63;
    const int w    = threadIdx.x >> 6;
    const int bid  = blockIdx.x;
    const int mg   = bid >> 7;
    const int n    = bid & 127;
    const int base_b = mg * 64 + w * 16;
    const int base_j = n * 16;
    const int r16  = lane & 15;
    const int q4   = lane >> 4;

    const int j = base_j + r16;
    const bf16x8* Ap = reinterpret_cast<const bf16x8*>(
        hbf_in + (size_t)(base_b + r16) * H_DIM + q4 * 8);
    const unsigned short* wslot = Wf + (size_t)(j >> 6) * 131072 + (size_t)(j & 63) * 8;

    f32x4 acc0 = {0.f, 0.f, 0.f, 0.f};
    f32x4 acc1 = {0.f, 0.f, 0.f, 0.f};
    #pragma unroll 8
    for (int kk = 0; kk < 32; ++kk) {
        bf16x8 a0 = Ap[kk * 4];
        bf16x8 a1 = Ap[kk * 4 + 128];
        bf16x8 b0 = *reinterpret_cast<const bf16x8*>(wslot + (size_t)(kk * 4 + q4) * 512);
        bf16x8 b1 = *reinterpret_cast<const bf16x8*>(wslot + (size_t)((kk + 32) * 4 + q4) * 512);
        acc0 = __builtin_amdgcn_mfma_f32_16x16x32_bf16(a0, b0, acc0, 0, 0, 0);
        acc1 = __builtin_amdgcn_mfma_f32_16x16x32_bf16(a1, b1, acc1, 0, 0, 0);
    }
    f32x4 h2h = acc0 + acc1;

    const float gamma = (j < N_HALF) ? -1.0f : 1.0f;
    const int brow0 = base_b + q4 * 4;
    #pragma unroll
    for (int i = 0; i < 4; ++i) {
        const int b = brow0 + i;
        const float v  = vel_t[b];
        const float hp = hprev[(size_t)b * H_DIM + j];
        const float pre = fmaf(v, gamma, 1.0f) + h2h[i];
        const float hn = OMA_F * hp + ALPHA_F * fmaxf(pre, 0.0f);
        acts_t[(size_t)b * H_DIM + j] = hn;
        hbf_out[(size_t)b * H_DIM + j] = f2bf(hn);
        if (outT) outT[(size_t)b * H_DIM + j] = hn;
    }
}

// ---------------------------------------------------------------------------
extern "C" void kernel_launch(void* const* d_in, const int* in_sizes, int n_in,
                              void* d_out, int out_size, void* d_ws, size_t ws_size,
                              hipStream_t stream) {
    const float* x       = (const float*)d_in[0];  // [T,B,IN]
    const float* hidden0 = (const float*)d_in[1];  // [B,H]
    const float* w_attr  = (const float*)d_in[2];  // [H,H]
    const float* w_in    = (const float*)d_in[3];  // [1,IN]

    float* acts = (float*)d_out;                               // [T,B,H]
    float* outT = acts + (size_t)T_STEPS * B_SZ * H_DIM;       // [B,H]

    unsigned char* ws = (unsigned char*)d_ws;
    unsigned short* Wf   = (unsigned short*)ws;                             // 8 MB
    unsigned short* hbf0 = (unsigned short*)(ws + ((size_t)8 << 20));       // 512 KB
    unsigned short* hbf1 = hbf0 + (size_t)B_SZ * H_DIM;                     // 512 KB
    float* vel = (float*)(ws + ((size_t)8 << 20) + (size_t)2 * B_SZ * H_DIM * 2); // 256 KB
    unsigned* flags = (unsigned*)(ws + ((size_t)8 << 20) + ((size_t)1 << 20) + (256 << 10)); // 4 KB

    hipMemsetAsync(flags, 0, 4096, stream);
    wf_kernel<<<dim3(32, 32), dim3(64, 4), 0, stream>>>(w_attr, Wf);
    vel_kernel<<<(T_STEPS * B_SZ + 255) / 256, 256, 0, stream>>>(x, w_in, vel);
    hbf_init_kernel<<<(B_SZ * H_DIM + 255) / 256, 256, 0, stream>>>(hidden0, hbf0);

    void* args[] = {(void*)&Wf, (void*)&hbf0, (void*)&hbf1, (void*)&vel,
                    (void*)&hidden0, (void*)&acts, (void*)&outT, (void*)&flags};
    hipError_t rc = hipLaunchCooperativeKernel(
        reinterpret_cast<void*>(ring_coop_kernel),
        dim3(256), dim3(512), args, 0, stream);

    if (rc != hipSuccess) {
        // fallback: per-step launches
        for (int t = 0; t < T_STEPS; ++t) {
            const unsigned short* hin = (t & 1) ? hbf1 : hbf0;
            unsigned short* hout      = (t & 1) ? hbf0 : hbf1;
            const float* hprev = (t == 0) ? hidden0 : acts + (size_t)(t - 1) * B_SZ * H_DIM;
            step_kernel<<<256, 256, 0, stream>>>(
                Wf, hin, hout, vel + (size_t)t * B_SZ, hprev,
                acts + (size_t)t * B_SZ * H_DIM,
                (t == T_STEPS - 1) ? outT : nullptr);
        }
    }
}